// Round 1
// baseline (883.902 us; speedup 1.0000x reference)
//
#include <hip/hip_runtime.h>
#include <hip/hip_bf16.h>

// Problem constants
#define S     2048
#define D     1024
#define NH    8
#define NKV   2
#define HD    128
#define WS_   64
#define E_    16
#define HDIM  512
#define TOPK  2
#define NTOK  S
#define NSLOT (S*TOPK)   // 4096

// ---------------------------------------------------------------------------
// RMSNorm: one block per row of 1024, 256 threads, float4 per thread
// ---------------------------------------------------------------------------
__global__ __launch_bounds__(256) void rmsnorm_kernel(
    const float* __restrict__ x, const float* __restrict__ w,
    float* __restrict__ out)
{
    int row = blockIdx.x, t = threadIdx.x;
    float4 v = ((const float4*)(x + (size_t)row * D))[t];
    float ss = v.x*v.x + v.y*v.y + v.z*v.z + v.w*v.w;
    #pragma unroll
    for (int off = 32; off; off >>= 1) ss += __shfl_xor(ss, off, 64);
    __shared__ float red[4];
    if ((t & 63) == 0) red[t >> 6] = ss;
    __syncthreads();
    float total = red[0] + red[1] + red[2] + red[3];
    float scale = rsqrtf(total * (1.0f / (float)D) + 1e-6f);
    float4 wv = ((const float4*)w)[t];
    float4 o;
    o.x = v.x * scale * wv.x; o.y = v.y * scale * wv.y;
    o.z = v.z * scale * wv.z; o.w = v.w * scale * wv.w;
    ((float4*)(out + (size_t)row * D))[t] = o;
}

// ---------------------------------------------------------------------------
// Tiled fp32 GEMM, 64x64 tile, BK=16, 256 threads, 4x4 per thread.
// V=0: C = A@W + bias
// V=1: o = A@W + bias + res; C = o; C2 = o   (wo projection + residual)
// V=2: MoE GEMM1: rows gathered via tok_idx, expert from blockIdx.z, silu
// V=3: MoE GEMM2: rows compact (hmid), atomicAdd(gate*(acc+bias)) into C[token]
// ---------------------------------------------------------------------------
template <int V>
__global__ __launch_bounds__(256) void gemm_k(
    const float* __restrict__ A, const float* __restrict__ Wb,
    const float* __restrict__ bb, float* __restrict__ C,
    float* __restrict__ C2, const float* __restrict__ res,
    int N, int K, int M,
    const int* __restrict__ offs, const int* __restrict__ tok_idx,
    const float* __restrict__ tok_gate)
{
    int e = (V >= 2) ? blockIdx.z : 0;
    const float* W    = (V >= 2) ? Wb + (size_t)e * K * M : Wb;
    const float* bias = (V >= 2) ? bb + (size_t)e * M     : bb;

    int row_lo, row_hi;
    if (V >= 2) {
        row_lo = offs[e] + blockIdx.y * 64;
        row_hi = offs[e + 1];
        if (row_lo >= row_hi) return;
    } else {
        row_lo = blockIdx.y * 64;
        row_hi = N;
    }
    int col0 = blockIdx.x * 64;

    __shared__ float As[16][65];
    __shared__ float Bs[16][64];

    int t  = threadIdx.x;
    int ar = t >> 2, ak = (t & 3) * 4;   // A-tile load: row-in-tile, k-offset
    int bk = t >> 4, bc = (t & 15) * 4;  // B-tile load
    int ty = t >> 4, tx = t & 15;

    int  arow_g = row_lo + ar;
    bool aval   = arow_g < row_hi;
    int  asrc   = 0;
    if (V == 2)      asrc = aval ? tok_idx[arow_g] : 0;
    else             asrc = arow_g;   // V==3: compact rows; V<2: plain

    float acc[4][4] = {};

    for (int k0 = 0; k0 < K; k0 += 16) {
        float4 av = make_float4(0.f, 0.f, 0.f, 0.f);
        if (aval) av = *(const float4*)&A[(size_t)asrc * K + k0 + ak];
        As[ak + 0][ar] = av.x; As[ak + 1][ar] = av.y;
        As[ak + 2][ar] = av.z; As[ak + 3][ar] = av.w;
        *(float4*)&Bs[bk][bc] = *(const float4*)&W[(size_t)(k0 + bk) * M + col0 + bc];
        __syncthreads();
        #pragma unroll
        for (int kk = 0; kk < 16; ++kk) {
            float a[4], b[4];
            #pragma unroll
            for (int i = 0; i < 4; ++i) a[i] = As[kk][ty * 4 + i];
            #pragma unroll
            for (int j = 0; j < 4; ++j) b[j] = Bs[kk][tx * 4 + j];
            #pragma unroll
            for (int i = 0; i < 4; ++i)
                #pragma unroll
                for (int j = 0; j < 4; ++j) acc[i][j] += a[i] * b[j];
        }
        __syncthreads();
    }

    #pragma unroll
    for (int i = 0; i < 4; ++i) {
        int r = row_lo + ty * 4 + i;
        if (r >= row_hi) continue;
        #pragma unroll
        for (int j = 0; j < 4; ++j) {
            int c = col0 + tx * 4 + j;
            float vacc = acc[i][j] + bias[c];
            if (V == 0) {
                C[(size_t)r * M + c] = vacc;
            } else if (V == 1) {
                float o = vacc + res[(size_t)r * M + c];
                C[(size_t)r * M + c]  = o;
                C2[(size_t)r * M + c] = o;
            } else if (V == 2) {
                C[(size_t)r * M + c] = vacc / (1.f + __expf(-vacc));  // silu
            } else {  // V == 3
                atomicAdd(&C[(size_t)tok_idx[r] * M + c], tok_gate[r] * vacc);
            }
        }
    }
}

// ---------------------------------------------------------------------------
// Sliding-window attention with sink softmax. One wave per (query, head).
// Lanes parallel over HD (2 floats each). WS=64 keys looped sequentially.
// ---------------------------------------------------------------------------
__global__ __launch_bounds__(256) void attn_kernel(
    const float* __restrict__ q, const float* __restrict__ k,
    const float* __restrict__ v, const float* __restrict__ sink_ptr,
    float* __restrict__ ao)
{
    int wave = threadIdx.x >> 6;
    int lane = threadIdx.x & 63;
    int gid  = blockIdx.x * 4 + wave;   // 0..S*NH-1
    int i = gid >> 3, h = gid & 7;
    int kvh = h >> 2;                   // NH/NKV = 4

    float2 qv = ((const float2*)(q + (size_t)i * D + h * HD))[lane];
    float sink = sink_ptr[0];
    const float rscale = 0.08838834764831845f;  // 1/sqrt(128)

    float m = -65504.f, denom = 0.f, ox = 0.f, oy = 0.f;
    int j0 = max(0, i - (WS_ - 1));
    for (int j = j0; j <= i; ++j) {
        float2 kv2 = ((const float2*)(k + (size_t)j * (NKV * HD) + kvh * HD))[lane];
        float part = qv.x * kv2.x + qv.y * kv2.y;
        #pragma unroll
        for (int off = 32; off; off >>= 1) part += __shfl_xor(part, off, 64);
        float s  = part * rscale;
        float mn = fmaxf(m, s);
        float c  = __expf(m - mn);
        float p  = __expf(s - mn);
        float2 vv = ((const float2*)(v + (size_t)j * (NKV * HD) + kvh * HD))[lane];
        denom = denom * c + p;
        ox = ox * c + p * vv.x;
        oy = oy * c + p * vv.y;
        m = mn;
    }
    float mf = fmaxf(m, sink);
    float c  = __expf(m - mf);
    denom = denom * c + __expf(sink - mf);
    float inv = c / denom;
    float2 o; o.x = ox * inv; o.y = oy * inv;
    ((float2*)(ao + (size_t)i * D + h * HD))[lane] = o;
}

// ---------------------------------------------------------------------------
// Router: one block per token. logits[16], top-2 gates, softmax colsum,
// expert histogram.
// ---------------------------------------------------------------------------
__global__ __launch_bounds__(256) void router_kernel(
    const float* __restrict__ h2, const float* __restrict__ rw,
    const float* __restrict__ rb, int* __restrict__ cnt,
    float* __restrict__ colsum, int* __restrict__ top_i,
    float* __restrict__ top_g)
{
    int tok = blockIdx.x, t = threadIdx.x;
    int e = t & 15, seg = t >> 4;
    const float* xr = h2 + (size_t)tok * D;
    float part = 0.f;
    int d0 = seg * 64;
    for (int d = d0; d < d0 + 64; ++d) part += xr[d] * rw[d * E_ + e];
    __shared__ float lpart[256];
    lpart[t] = part;
    __syncthreads();
    __shared__ float logits[E_];
    if (t < E_) {
        float s = 0.f;
        for (int sg = 0; sg < 16; ++sg) s += lpart[sg * 16 + t];
        logits[t] = (s + rb[t]) * 10.0f;   // /0.1
    }
    __syncthreads();
    __shared__ float sm[2];
    if (t == 0) {
        float mx = logits[0];
        for (int x = 1; x < E_; ++x) mx = fmaxf(mx, logits[x]);
        float ps = 0.f;
        for (int x = 0; x < E_; ++x) ps += __expf(logits[x] - mx);
        sm[0] = mx; sm[1] = ps;
        // top-2 (ties -> lowest index, matching lax.top_k)
        int i0 = 0; float v0 = logits[0];
        for (int x = 1; x < E_; ++x) if (logits[x] > v0) { v0 = logits[x]; i0 = x; }
        int i1 = -1; float v1 = -3.4e38f;
        for (int x = 0; x < E_; ++x) {
            if (x == i0) continue;
            if (logits[x] > v1) { v1 = logits[x]; i1 = x; }
        }
        float e1 = __expf(v1 - v0);        // v0 >= v1
        float g0 = 1.f / (1.f + e1);
        float g1 = e1 * g0;
        top_i[tok * 2 + 0] = i0; top_g[tok * 2 + 0] = g0;
        top_i[tok * 2 + 1] = i1; top_g[tok * 2 + 1] = g1;
        atomicAdd(&cnt[i0], 1);
        atomicAdd(&cnt[i1], 1);
    }
    __syncthreads();
    if (t < E_) atomicAdd(&colsum[t], __expf(logits[t] - sm[0]) / sm[1]);
}

// ---------------------------------------------------------------------------
// Prefix offsets + aux loss
// ---------------------------------------------------------------------------
__global__ void offsets_kernel(const int* __restrict__ cnt, int* __restrict__ offs,
                               int* __restrict__ cursor,
                               const float* __restrict__ colsum,
                               float* __restrict__ aux_out)
{
    if (threadIdx.x == 0) {
        int acc = 0;
        for (int e = 0; e < E_; ++e) { offs[e] = acc; cursor[e] = acc; acc += cnt[e]; }
        offs[E_] = acc;
        float s = 0.f;
        for (int e = 0; e < E_; ++e) s += colsum[e] * colsum[e];
        *aux_out = s / (float)E_ * 1e-5f;
    }
}

// ---------------------------------------------------------------------------
// Scatter tokens into expert-contiguous compact arrays
// ---------------------------------------------------------------------------
__global__ __launch_bounds__(256) void scatter_kernel(
    const int* __restrict__ top_i, const float* __restrict__ top_g,
    int* __restrict__ cursor, int* __restrict__ tok_idx,
    float* __restrict__ tok_gate)
{
    int tok = blockIdx.x * 256 + threadIdx.x;
    if (tok >= NTOK) return;
    for (int s = 0; s < TOPK; ++s) {
        int e = top_i[tok * 2 + s];
        int pos = atomicAdd(&cursor[e], 1);
        tok_idx[pos]  = tok;
        tok_gate[pos] = top_g[tok * 2 + s];
    }
}

// ---------------------------------------------------------------------------
extern "C" void kernel_launch(void* const* d_in, const int* in_sizes, int n_in,
                              void* d_out, int out_size, void* d_ws, size_t ws_size,
                              hipStream_t stream)
{
    const float* x        = (const float*)d_in[0];
    const float* norm1_w  = (const float*)d_in[1];
    const float* wq       = (const float*)d_in[2];
    const float* bq       = (const float*)d_in[3];
    const float* wk       = (const float*)d_in[4];
    const float* bk       = (const float*)d_in[5];
    const float* wv       = (const float*)d_in[6];
    const float* bv       = (const float*)d_in[7];
    const float* wo       = (const float*)d_in[8];
    const float* bo       = (const float*)d_in[9];
    const float* sink     = (const float*)d_in[10];
    const float* norm2_w  = (const float*)d_in[11];
    const float* router_w = (const float*)d_in[12];
    const float* router_b = (const float*)d_in[13];
    const float* w1       = (const float*)d_in[14];
    const float* b1       = (const float*)d_in[15];
    const float* w2       = (const float*)d_in[16];
    const float* b2       = (const float*)d_in[17];
    float* out = (float*)d_out;

    // workspace layout (floats)
    float* wsf  = (float*)d_ws;
    float* h    = wsf;                 // [S,D]
    float* qb   = h    + (size_t)S * D;
    float* kb   = qb   + (size_t)S * D;        // [S, NKV*HD]
    float* vb   = kb   + (size_t)S * NKV * HD;
    float* ao   = vb   + (size_t)S * NKV * HD; // [S,D]
    float* x1   = ao   + (size_t)S * D;
    float* h2   = x1   + (size_t)S * D;
    float* hmid = h2   + (size_t)S * D;        // [NSLOT, HDIM]
    float* fext = hmid + (size_t)NSLOT * HDIM;
    int*   cnt      = (int*)fext;              // 16
    float* colsum   = fext + 16;               // 16
    int*   offs     = (int*)(fext + 32);       // 17
    int*   cursor   = offs + 17;               // 16
    int*   top_i    = cursor + 16;             // 4096
    float* top_g    = (float*)(top_i + NSLOT);
    int*   tok_idx  = (int*)(top_g + NSLOT);
    float* tok_gate = (float*)(tok_idx + NSLOT);

    hipMemsetAsync(cnt, 0, 32 * sizeof(float), stream);  // cnt + colsum

    // 1) h = rmsnorm(x, norm1_w)
    rmsnorm_kernel<<<S, 256, 0, stream>>>(x, norm1_w, h);

    // 2) q/k/v projections
    gemm_k<0><<<dim3(D / 64, S / 64), 256, 0, stream>>>(
        h, wq, bq, qb, nullptr, nullptr, S, D, D, nullptr, nullptr, nullptr);
    gemm_k<0><<<dim3((NKV * HD) / 64, S / 64), 256, 0, stream>>>(
        h, wk, bk, kb, nullptr, nullptr, S, D, NKV * HD, nullptr, nullptr, nullptr);
    gemm_k<0><<<dim3((NKV * HD) / 64, S / 64), 256, 0, stream>>>(
        h, wv, bv, vb, nullptr, nullptr, S, D, NKV * HD, nullptr, nullptr, nullptr);

    // 3) sliding-window attention
    attn_kernel<<<(S * NH) / 4, 256, 0, stream>>>(qb, kb, vb, sink, ao);

    // 4) x1 = x + ao@wo + bo   (also seed d_out with x1)
    gemm_k<1><<<dim3(D / 64, S / 64), 256, 0, stream>>>(
        ao, wo, bo, x1, out, x, S, D, D, nullptr, nullptr, nullptr);

    // 5) h2 = rmsnorm(x1, norm2_w)
    rmsnorm_kernel<<<S, 256, 0, stream>>>(x1, norm2_w, h2);

    // 6) router: logits, top2, gates, histogram, softmax colsum
    router_kernel<<<NTOK, 256, 0, stream>>>(h2, router_w, router_b,
                                            cnt, colsum, top_i, top_g);

    // 7) offsets + aux loss -> out[S*D]
    offsets_kernel<<<1, 64, 0, stream>>>(cnt, offs, cursor, colsum,
                                         out + (size_t)S * D);

    // 8) scatter token slots expert-contiguously
    scatter_kernel<<<(NTOK + 255) / 256, 256, 0, stream>>>(
        top_i, top_g, cursor, tok_idx, tok_gate);

    // 9) MoE GEMM1: hmid = silu(gather(h2) @ w1[e] + b1[e])
    gemm_k<2><<<dim3(HDIM / 64, NSLOT / 64, E_), 256, 0, stream>>>(
        h2, w1, b1, hmid, nullptr, nullptr, NSLOT, D, HDIM,
        offs, tok_idx, tok_gate);

    // 10) MoE GEMM2: out[token] += gate * (hmid @ w2[e] + b2[e])
    gemm_k<3><<<dim3(D / 64, NSLOT / 64, E_), 256, 0, stream>>>(
        hmid, w2, b2, out, nullptr, nullptr, NSLOT, HDIM, D,
        offs, tok_idx, tok_gate);
}

// Round 2
// 513.397 us; speedup vs baseline: 1.7217x; 1.7217x over previous
//
#include <hip/hip_runtime.h>
#include <hip/hip_bf16.h>

// Problem constants
#define S     2048
#define D     1024
#define NH    8
#define NKV   2
#define HD    128
#define WS_   64
#define E_    16
#define HDIM  512
#define TOPK  2
#define NTOK  S
#define NSLOT (S*TOPK)         // 4096
#define QKV_M (D + 2*NKV*HD)   // 1536 fused q|k|v columns
#define KOFF  D                // 1024
#define VOFF  (D + NKV*HD)     // 1280

typedef __attribute__((ext_vector_type(8))) short bf16x8;
typedef __attribute__((ext_vector_type(4))) float floatx4;

__device__ inline short f2bf(float f) {
    __hip_bfloat16 b = __float2bfloat16(f);
    return *reinterpret_cast<short*>(&b);
}

// ---------------------------------------------------------------------------
// Transpose + fp32->bf16 convert: in [K,M] fp32 -> outT [M,K] bf16.
// 32x32 tiles via LDS, batched over blockIdx.z (experts).
// ---------------------------------------------------------------------------
__global__ __launch_bounds__(256) void tconv_kernel(
    const float* __restrict__ in, short* __restrict__ outT,
    int K, int M, long in_es, long out_es)
{
    const float* ine = in + (size_t)blockIdx.z * in_es;
    short* oute = outT + (size_t)blockIdx.z * out_es;
    int k0 = blockIdx.y * 32, m0 = blockIdx.x * 32;
    __shared__ float tile[32][33];
    int t = threadIdx.x;
    int r = t >> 3, c4 = (t & 7) * 4;
    float4 v = *(const float4*)&ine[(size_t)(k0 + r) * M + m0 + c4];
    tile[r][c4 + 0] = v.x; tile[r][c4 + 1] = v.y;
    tile[r][c4 + 2] = v.z; tile[r][c4 + 3] = v.w;
    __syncthreads();
    short4 o;
    o.x = f2bf(tile[c4 + 0][r]);
    o.y = f2bf(tile[c4 + 1][r]);
    o.z = f2bf(tile[c4 + 2][r]);
    o.w = f2bf(tile[c4 + 3][r]);
    *(short4*)&oute[(size_t)(m0 + r) * K + k0 + c4] = o;
}

__global__ void bias_concat_kernel(const float* __restrict__ bq,
                                   const float* __restrict__ bk,
                                   const float* __restrict__ bv,
                                   float* __restrict__ bqkv)
{
    int t = blockIdx.x * 256 + threadIdx.x;
    if (t < D) bqkv[t] = bq[t];
    else if (t < D + NKV * HD) bqkv[t] = bk[t - D];
    else if (t < QKV_M) bqkv[t] = bv[t - D - NKV * HD];
}

// ---------------------------------------------------------------------------
// RMSNorm: one block per row, optional fp32 and bf16 outputs
// ---------------------------------------------------------------------------
__global__ __launch_bounds__(256) void rmsnorm_kernel(
    const float* __restrict__ x, const float* __restrict__ w,
    float* __restrict__ outf, short* __restrict__ outb)
{
    int row = blockIdx.x, t = threadIdx.x;
    float4 v = ((const float4*)(x + (size_t)row * D))[t];
    float ss = v.x*v.x + v.y*v.y + v.z*v.z + v.w*v.w;
    #pragma unroll
    for (int off = 32; off; off >>= 1) ss += __shfl_xor(ss, off, 64);
    __shared__ float red[4];
    if ((t & 63) == 0) red[t >> 6] = ss;
    __syncthreads();
    float total = red[0] + red[1] + red[2] + red[3];
    float scale = rsqrtf(total * (1.0f / (float)D) + 1e-6f);
    float4 wv = ((const float4*)w)[t];
    float4 o;
    o.x = v.x * scale * wv.x; o.y = v.y * scale * wv.y;
    o.z = v.z * scale * wv.z; o.w = v.w * scale * wv.w;
    if (outf) ((float4*)(outf + (size_t)row * D))[t] = o;
    if (outb) {
        short4 ob;
        ob.x = f2bf(o.x); ob.y = f2bf(o.y); ob.z = f2bf(o.z); ob.w = f2bf(o.w);
        ((short4*)(outb + (size_t)row * D))[t] = ob;
    }
}

// ---------------------------------------------------------------------------
// bf16 MFMA GEMM: C[N,M] = A[N,K](bf16) @ Bt[M,K]^T(bf16) + bias
// 128x128 tile, BK=32, 256 threads = 4 waves in 2x2, each wave 64x64
// (4x4 grid of 16x16x32 MFMA tiles).
// V=0: C fp32 (fused QKV)
// V=1: o = acc+bias+res; C=o, C2=o (WO + residual, seeds d_out)
// V=2: MoE1: A rows gathered via tok_idx, silu, bf16 out (hmid)
// V=3: MoE2: compact A rows; atomicAdd(gate*(acc+bias)) into C[tok_idx[r]]
// ---------------------------------------------------------------------------
template <int V>
__global__ __launch_bounds__(256) void mgemm(
    const short* __restrict__ A, const short* __restrict__ Bt,
    const float* __restrict__ bias, float* __restrict__ C,
    short* __restrict__ Cb, float* __restrict__ C2,
    const float* __restrict__ res, int K, int M,
    const int* __restrict__ offs, const int* __restrict__ tok_idx,
    const float* __restrict__ tok_gate)
{
    int e = (V >= 2) ? blockIdx.z : 0;
    const short* Bte = (V >= 2) ? Bt + (size_t)e * M * K : Bt;
    const float* be  = (V >= 2) ? bias + (size_t)e * M : bias;

    int row_lo, row_hi;
    if (V >= 2) {
        row_lo = offs[e] + blockIdx.y * 128;
        row_hi = offs[e + 1];
        if (row_lo >= row_hi) return;
    } else {
        row_lo = blockIdx.y * 128;
        row_hi = 1 << 30;
    }
    int col0 = blockIdx.x * 128;

    __shared__ short As[128 * 40];   // row stride 40 shorts (80B, 16B-aligned)
    __shared__ short Bs[128 * 40];

    int t = threadIdx.x;
    int srow  = t >> 1;          // 0..127
    int skoff = (t & 1) * 16;    // 0 or 16

    int  agrow = row_lo + srow;
    bool aval  = true;
    int  asrc  = agrow;
    if (V == 2) { aval = agrow < row_hi; asrc = aval ? tok_idx[agrow] : 0; }
    if (V == 3) { aval = agrow < row_hi; if (!aval) asrc = 0; }
    const short* aptr = A   + (size_t)asrc * K + skoff;
    const short* bptr = Bte + (size_t)(col0 + srow) * K + skoff;
    short* as_dst = &As[srow * 40 + skoff];
    short* bs_dst = &Bs[srow * 40 + skoff];

    int lane = t & 63, wave = t >> 6;
    int wm = (wave & 1) * 64, wn = (wave >> 1) * 64;
    int rin = lane & 15, quad = lane >> 4;

    floatx4 acc[4][4];
    #pragma unroll
    for (int i = 0; i < 4; ++i)
        #pragma unroll
        for (int j = 0; j < 4; ++j)
            acc[i][j] = (floatx4){0.f, 0.f, 0.f, 0.f};

    for (int k0 = 0; k0 < K; k0 += 32) {
        float4 z = make_float4(0.f, 0.f, 0.f, 0.f);
        float4 av0 = aval ? *(const float4*)(aptr + k0)     : z;
        float4 av1 = aval ? *(const float4*)(aptr + k0 + 8) : z;
        float4 bv0 = *(const float4*)(bptr + k0);
        float4 bv1 = *(const float4*)(bptr + k0 + 8);
        __syncthreads();   // WAR vs previous iteration's fragment reads
        *(float4*)(as_dst)     = av0;
        *(float4*)(as_dst + 8) = av1;
        *(float4*)(bs_dst)     = bv0;
        *(float4*)(bs_dst + 8) = bv1;
        __syncthreads();
        bf16x8 af[4], bfr[4];
        #pragma unroll
        for (int i = 0; i < 4; ++i)
            af[i] = *(const bf16x8*)&As[(wm + i * 16 + rin) * 40 + quad * 8];
        #pragma unroll
        for (int j = 0; j < 4; ++j)
            bfr[j] = *(const bf16x8*)&Bs[(wn + j * 16 + rin) * 40 + quad * 8];
        #pragma unroll
        for (int i = 0; i < 4; ++i)
            #pragma unroll
            for (int j = 0; j < 4; ++j)
                acc[i][j] = __builtin_amdgcn_mfma_f32_16x16x32_bf16(
                    af[i], bfr[j], acc[i][j], 0, 0, 0);
    }

    // Epilogue. C/D layout: col = lane&15, row = quad*4 + reg  [m89-verified]
    #pragma unroll
    for (int i = 0; i < 4; ++i) {
        #pragma unroll
        for (int j = 0; j < 4; ++j) {
            int cg = col0 + wn + j * 16 + rin;
            #pragma unroll
            for (int rr = 0; rr < 4; ++rr) {
                int rg = row_lo + wm + i * 16 + quad * 4 + rr;
                float val = acc[i][j][rr];
                if (V == 0) {
                    C[(size_t)rg * M + cg] = val + be[cg];
                } else if (V == 1) {
                    float o = val + be[cg] + res[(size_t)rg * M + cg];
                    C[(size_t)rg * M + cg]  = o;
                    C2[(size_t)rg * M + cg] = o;
                } else if (V == 2) {
                    if (rg < row_hi) {
                        float vb_ = val + be[cg];
                        Cb[(size_t)rg * M + cg] = f2bf(vb_ / (1.f + __expf(-vb_)));
                    }
                } else {
                    if (rg < row_hi)
                        atomicAdd(&C[(size_t)tok_idx[rg] * M + cg],
                                  tok_gate[rg] * (val + be[cg]));
                }
            }
        }
    }
}

// ---------------------------------------------------------------------------
// Sliding-window attention with sink softmax; reads fused qkv fp32,
// writes bf16 ao. One wave per (query, head).
// ---------------------------------------------------------------------------
__global__ __launch_bounds__(256) void attn_kernel(
    const float* __restrict__ qkv, const float* __restrict__ sink_ptr,
    short* __restrict__ ao)
{
    int wave = threadIdx.x >> 6;
    int lane = threadIdx.x & 63;
    int gid  = blockIdx.x * 4 + wave;   // 0..S*NH-1
    int i = gid >> 3, h = gid & 7;
    int kvh = h >> 2;                   // NH/NKV = 4

    float2 qv = ((const float2*)(qkv + (size_t)i * QKV_M + h * HD))[lane];
    float sink = sink_ptr[0];
    const float rscale = 0.08838834764831845f;  // 1/sqrt(128)

    float m = -65504.f, denom = 0.f, ox = 0.f, oy = 0.f;
    int j0 = max(0, i - (WS_ - 1));
    for (int j = j0; j <= i; ++j) {
        float2 kv2 = ((const float2*)(qkv + (size_t)j * QKV_M + KOFF + kvh * HD))[lane];
        float part = qv.x * kv2.x + qv.y * kv2.y;
        #pragma unroll
        for (int off = 32; off; off >>= 1) part += __shfl_xor(part, off, 64);
        float s  = part * rscale;
        float mn = fmaxf(m, s);
        float c  = __expf(m - mn);
        float p  = __expf(s - mn);
        float2 vv = ((const float2*)(qkv + (size_t)j * QKV_M + VOFF + kvh * HD))[lane];
        denom = denom * c + p;
        ox = ox * c + p * vv.x;
        oy = oy * c + p * vv.y;
        m = mn;
    }
    float mf = fmaxf(m, sink);
    float c  = __expf(m - mf);
    denom = denom * c + __expf(sink - mf);
    float inv = c / denom;
    short2 o2;
    o2.x = f2bf(ox * inv);
    o2.y = f2bf(oy * inv);
    ((short2*)(ao + (size_t)i * D + h * HD))[lane] = o2;
}

// ---------------------------------------------------------------------------
// Router: fp32 logits (top-k selection must stay fp32-exact vs reference)
// ---------------------------------------------------------------------------
__global__ __launch_bounds__(256) void router_kernel(
    const float* __restrict__ h2, const float* __restrict__ rw,
    const float* __restrict__ rb, int* __restrict__ cnt,
    float* __restrict__ colsum, int* __restrict__ top_i,
    float* __restrict__ top_g)
{
    int tok = blockIdx.x, t = threadIdx.x;
    int e = t & 15, seg = t >> 4;
    const float* xr = h2 + (size_t)tok * D;
    float part = 0.f;
    int d0 = seg * 64;
    for (int d = d0; d < d0 + 64; ++d) part += xr[d] * rw[d * E_ + e];
    __shared__ float lpart[256];
    lpart[t] = part;
    __syncthreads();
    __shared__ float logits[E_];
    if (t < E_) {
        float s = 0.f;
        for (int sg = 0; sg < 16; ++sg) s += lpart[sg * 16 + t];
        logits[t] = (s + rb[t]) * 10.0f;   // /0.1
    }
    __syncthreads();
    __shared__ float sm[2];
    if (t == 0) {
        float mx = logits[0];
        for (int x = 1; x < E_; ++x) mx = fmaxf(mx, logits[x]);
        float ps = 0.f;
        for (int x = 0; x < E_; ++x) ps += __expf(logits[x] - mx);
        sm[0] = mx; sm[1] = ps;
        int i0 = 0; float v0 = logits[0];
        for (int x = 1; x < E_; ++x) if (logits[x] > v0) { v0 = logits[x]; i0 = x; }
        int i1 = -1; float v1 = -3.4e38f;
        for (int x = 0; x < E_; ++x) {
            if (x == i0) continue;
            if (logits[x] > v1) { v1 = logits[x]; i1 = x; }
        }
        float e1 = __expf(v1 - v0);
        float g0 = 1.f / (1.f + e1);
        float g1 = e1 * g0;
        top_i[tok * 2 + 0] = i0; top_g[tok * 2 + 0] = g0;
        top_i[tok * 2 + 1] = i1; top_g[tok * 2 + 1] = g1;
        atomicAdd(&cnt[i0], 1);
        atomicAdd(&cnt[i1], 1);
    }
    __syncthreads();
    if (t < E_) atomicAdd(&colsum[t], __expf(logits[t] - sm[0]) / sm[1]);
}

__global__ void offsets_kernel(const int* __restrict__ cnt, int* __restrict__ offs,
                               int* __restrict__ cursor,
                               const float* __restrict__ colsum,
                               float* __restrict__ aux_out)
{
    if (threadIdx.x == 0) {
        int acc = 0;
        for (int e = 0; e < E_; ++e) { offs[e] = acc; cursor[e] = acc; acc += cnt[e]; }
        offs[E_] = acc;
        float s = 0.f;
        for (int e = 0; e < E_; ++e) s += colsum[e] * colsum[e];
        *aux_out = s / (float)E_ * 1e-5f;
    }
}

__global__ __launch_bounds__(256) void scatter_kernel(
    const int* __restrict__ top_i, const float* __restrict__ top_g,
    int* __restrict__ cursor, int* __restrict__ tok_idx,
    float* __restrict__ tok_gate)
{
    int tok = blockIdx.x * 256 + threadIdx.x;
    if (tok >= NTOK) return;
    for (int s = 0; s < TOPK; ++s) {
        int e = top_i[tok * 2 + s];
        int pos = atomicAdd(&cursor[e], 1);
        tok_idx[pos]  = tok;
        tok_gate[pos] = top_g[tok * 2 + s];
    }
}

// ---------------------------------------------------------------------------
extern "C" void kernel_launch(void* const* d_in, const int* in_sizes, int n_in,
                              void* d_out, int out_size, void* d_ws, size_t ws_size,
                              hipStream_t stream)
{
    const float* x        = (const float*)d_in[0];
    const float* norm1_w  = (const float*)d_in[1];
    const float* wq       = (const float*)d_in[2];
    const float* bq       = (const float*)d_in[3];
    const float* wk       = (const float*)d_in[4];
    const float* bk       = (const float*)d_in[5];
    const float* wv       = (const float*)d_in[6];
    const float* bv       = (const float*)d_in[7];
    const float* wo       = (const float*)d_in[8];
    const float* bo       = (const float*)d_in[9];
    const float* sink     = (const float*)d_in[10];
    const float* norm2_w  = (const float*)d_in[11];
    const float* router_w = (const float*)d_in[12];
    const float* router_b = (const float*)d_in[13];
    const float* w1       = (const float*)d_in[14];
    const float* b1       = (const float*)d_in[15];
    const float* w2       = (const float*)d_in[16];
    const float* b2       = (const float*)d_in[17];
    float* out = (float*)d_out;

    // workspace layout
    char* w = (char*)d_ws;
    auto alloc = [&](size_t bytes) {
        char* p = w; w += (bytes + 255) & ~255ull; return p;
    };
    short* wqkvT = (short*)alloc((size_t)QKV_M * D * 2);       // [1536][1024]
    short* woT   = (short*)alloc((size_t)D * D * 2);           // [1024][1024]
    short* w1T   = (short*)alloc((size_t)E_ * HDIM * D * 2);   // [16][512][1024]
    short* w2T   = (short*)alloc((size_t)E_ * D * HDIM * 2);   // [16][1024][512]
    float* bqkv  = (float*)alloc(QKV_M * 4);
    short* h_bf  = (short*)alloc((size_t)S * D * 2);
    float* qkv   = (float*)alloc((size_t)S * QKV_M * 4);
    float* x1    = (float*)alloc((size_t)S * D * 4);
    float* h2    = (float*)alloc((size_t)S * D * 4);
    short* h2b   = (short*)alloc((size_t)S * D * 2);
    int*   cnt      = (int*)alloc(16 * 4);
    float* colsum   = (float*)alloc(16 * 4);
    int*   offs     = (int*)alloc(17 * 4);
    int*   cursor   = (int*)alloc(16 * 4);
    int*   top_i    = (int*)alloc((size_t)NSLOT * 4);
    float* top_g    = (float*)alloc((size_t)NSLOT * 4);
    int*   tok_idx  = (int*)alloc((size_t)NSLOT * 4);
    float* tok_gate = (float*)alloc((size_t)NSLOT * 4);
    // aliases (lifetimes don't overlap):
    short* ao_bf = h_bf;          // h_bf dead after QKV GEMM; attn writes ao after
    short* hmid  = (short*)qkv;   // qkv dead after attention; MoE1 writes hmid after

    hipMemsetAsync(cnt, 0, 16 * 4, stream);
    hipMemsetAsync(colsum, 0, 16 * 4, stream);

    // weight convert+transpose -> bf16 [M][K]
    tconv_kernel<<<dim3(D / 32, D / 32), 256, 0, stream>>>(
        wq, wqkvT, D, D, 0, 0);
    tconv_kernel<<<dim3((NKV * HD) / 32, D / 32), 256, 0, stream>>>(
        wk, wqkvT + (size_t)KOFF * D, D, NKV * HD, 0, 0);
    tconv_kernel<<<dim3((NKV * HD) / 32, D / 32), 256, 0, stream>>>(
        wv, wqkvT + (size_t)VOFF * D, D, NKV * HD, 0, 0);
    tconv_kernel<<<dim3(D / 32, D / 32), 256, 0, stream>>>(
        wo, woT, D, D, 0, 0);
    tconv_kernel<<<dim3(HDIM / 32, D / 32, E_), 256, 0, stream>>>(
        w1, w1T, D, HDIM, (long)D * HDIM, (long)HDIM * D);
    tconv_kernel<<<dim3(D / 32, HDIM / 32, E_), 256, 0, stream>>>(
        w2, w2T, HDIM, D, (long)HDIM * D, (long)D * HDIM);
    bias_concat_kernel<<<QKV_M / 256, 256, 0, stream>>>(bq, bk, bv, bqkv);

    // 1) h = rmsnorm(x) -> bf16
    rmsnorm_kernel<<<S, 256, 0, stream>>>(x, norm1_w, nullptr, h_bf);

    // 2) fused QKV: qkv = h @ [wq|wk|wv] + [bq|bk|bv]
    mgemm<0><<<dim3(QKV_M / 128, S / 128), 256, 0, stream>>>(
        h_bf, wqkvT, bqkv, qkv, nullptr, nullptr, nullptr, D, QKV_M,
        nullptr, nullptr, nullptr);

    // 3) attention -> bf16 ao
    attn_kernel<<<(S * NH) / 4, 256, 0, stream>>>(qkv, sink, ao_bf);

    // 4) x1 = x + ao@wo + bo  (also seeds d_out)
    mgemm<1><<<dim3(D / 128, S / 128), 256, 0, stream>>>(
        ao_bf, woT, bo, x1, nullptr, out, x, D, D,
        nullptr, nullptr, nullptr);

    // 5) h2 = rmsnorm(x1) -> fp32 (router) + bf16 (MoE)
    rmsnorm_kernel<<<S, 256, 0, stream>>>(x1, norm2_w, h2, h2b);

    // 6-8) router, offsets+aux, scatter
    router_kernel<<<NTOK, 256, 0, stream>>>(h2, router_w, router_b,
                                            cnt, colsum, top_i, top_g);
    offsets_kernel<<<1, 64, 0, stream>>>(cnt, offs, cursor, colsum,
                                         out + (size_t)S * D);
    scatter_kernel<<<(NTOK + 255) / 256, 256, 0, stream>>>(
        top_i, top_g, cursor, tok_idx, tok_gate);

    // 9) MoE GEMM1: hmid = silu(gather(h2b) @ w1[e] + b1[e]) -> bf16
    mgemm<2><<<dim3(HDIM / 128, NSLOT / 128, E_), 256, 0, stream>>>(
        h2b, w1T, b1, nullptr, hmid, nullptr, nullptr, D, HDIM,
        offs, tok_idx, tok_gate);

    // 10) MoE GEMM2: out[token] += gate * (hmid @ w2[e] + b2[e])
    mgemm<3><<<dim3(D / 128, NSLOT / 128, E_), 256, 0, stream>>>(
        hmid, w2T, b2, out, nullptr, nullptr, nullptr, HDIM, D,
        offs, tok_idx, tok_gate);
}

// Round 3
// 482.232 us; speedup vs baseline: 1.8329x; 1.0646x over previous
//
#include <hip/hip_runtime.h>
#include <hip/hip_bf16.h>

// Problem constants
#define S     2048
#define D     1024
#define NH    8
#define NKV   2
#define HD    128
#define WS_   64
#define E_    16
#define HDIM  512
#define TOPK  2
#define NTOK  S
#define NSLOT (S*TOPK)         // 4096
#define QKV_M (D + 2*NKV*HD)   // 1536 fused q|k|v columns
#define KOFF  D                // 1024
#define VOFF  (D + NKV*HD)     // 1280
#define QB    8                // queries per attention block
#define WROWS (QB + WS_ - 1)   // 71 key rows per window
#define KVPAD 132              // LDS row stride (floats): 16B-aligned, %32==4 -> conflict-optimal

typedef __attribute__((ext_vector_type(8))) short bf16x8;
typedef __attribute__((ext_vector_type(4))) float floatx4;

__device__ inline short f2bf(float f) {
    __hip_bfloat16 b = __float2bfloat16(f);
    return *reinterpret_cast<short*>(&b);
}

// ---------------------------------------------------------------------------
// All weight prep in ONE launch: 6 transpose+convert regions + bias concat.
// 32x32 fp32->bf16 transpose tiles; block id decodes region.
// ---------------------------------------------------------------------------
__global__ __launch_bounds__(256) void tconv_all(
    const float* __restrict__ wq, const float* __restrict__ wk,
    const float* __restrict__ wv, const float* __restrict__ wo,
    const float* __restrict__ w1, const float* __restrict__ w2,
    const float* __restrict__ bq, const float* __restrict__ bk,
    const float* __restrict__ bv,
    short* __restrict__ wqkvT, short* __restrict__ woT,
    short* __restrict__ w1T, short* __restrict__ w2T,
    float* __restrict__ bqkv)
{
    int id = blockIdx.x;
    if (id >= 18944) {                       // 6 bias-concat blocks
        int t = (id - 18944) * 256 + threadIdx.x;
        if (t < D) bqkv[t] = bq[t];
        else if (t < VOFF) bqkv[t] = bk[t - D];
        else bqkv[t] = bv[t - VOFF];
        return;
    }
    const float* in; short* outp; int K, M, mx, ky;
    if (id < 1024)      { in = wq; outp = wqkvT;                  K = D; M = D;   int l = id;        mx = l & 31; ky = l >> 5; }
    else if (id < 1280) { in = wk; outp = wqkvT + (size_t)KOFF*D; K = D; M = 256; int l = id - 1024; mx = l & 7;  ky = l >> 3; }
    else if (id < 1536) { in = wv; outp = wqkvT + (size_t)VOFF*D; K = D; M = 256; int l = id - 1280; mx = l & 7;  ky = l >> 3; }
    else if (id < 2560) { in = wo; outp = woT;                    K = D; M = D;   int l = id - 1536; mx = l & 31; ky = l >> 5; }
    else if (id < 10752){ int l = id - 2560;  int e = l >> 9; int r = l & 511;
                          in = w1 + (size_t)e * D * HDIM; outp = w1T + (size_t)e * D * HDIM;
                          K = D; M = HDIM; mx = r & 15; ky = r >> 4; }
    else                { int l = id - 10752; int e = l >> 9; int r = l & 511;
                          in = w2 + (size_t)e * D * HDIM; outp = w2T + (size_t)e * D * HDIM;
                          K = HDIM; M = D; mx = r & 31; ky = r >> 5; }
    __shared__ float tile[32][33];
    int t = threadIdx.x, r = t >> 3, c4 = (t & 7) * 4;
    int k0 = ky * 32, m0 = mx * 32;
    float4 v = *(const float4*)&in[(size_t)(k0 + r) * M + m0 + c4];
    tile[r][c4 + 0] = v.x; tile[r][c4 + 1] = v.y;
    tile[r][c4 + 2] = v.z; tile[r][c4 + 3] = v.w;
    __syncthreads();
    short4 o;
    o.x = f2bf(tile[c4 + 0][r]);
    o.y = f2bf(tile[c4 + 1][r]);
    o.z = f2bf(tile[c4 + 2][r]);
    o.w = f2bf(tile[c4 + 3][r]);
    *(short4*)&outp[(size_t)(m0 + r) * K + k0 + c4] = o;
}

// ---------------------------------------------------------------------------
// RMSNorm (attention pre-norm): fp32 in -> bf16 out
// ---------------------------------------------------------------------------
__global__ __launch_bounds__(256) void rmsnorm_kernel(
    const float* __restrict__ x, const float* __restrict__ w,
    short* __restrict__ outb)
{
    int row = blockIdx.x, t = threadIdx.x;
    float4 v = ((const float4*)(x + (size_t)row * D))[t];
    float ss = v.x*v.x + v.y*v.y + v.z*v.z + v.w*v.w;
    #pragma unroll
    for (int off = 32; off; off >>= 1) ss += __shfl_xor(ss, off, 64);
    __shared__ float red[4];
    if ((t & 63) == 0) red[t >> 6] = ss;
    __syncthreads();
    float total = red[0] + red[1] + red[2] + red[3];
    float scale = rsqrtf(total * (1.0f / (float)D) + 1e-6f);
    float4 wv = ((const float4*)w)[t];
    short4 ob;
    ob.x = f2bf(v.x * scale * wv.x); ob.y = f2bf(v.y * scale * wv.y);
    ob.z = f2bf(v.z * scale * wv.z); ob.w = f2bf(v.w * scale * wv.w);
    ((short4*)(outb + (size_t)row * D))[t] = ob;
}

// ---------------------------------------------------------------------------
// bf16 MFMA GEMM: C[N,M] = A[N,K](bf16) @ Bt[M,K]^T(bf16) + bias
// 128x64 block tile, BK=32, 4 waves (2x2): each wave 64 rows x 32 cols.
// V=0: C fp32 (fused QKV)   V=1: +res, dual store (WO)
// V=2: MoE1 gather+silu->bf16   V=3: MoE2 atomic scatter
// ---------------------------------------------------------------------------
template <int V>
__global__ __launch_bounds__(256) void mgemm(
    const short* __restrict__ A, const short* __restrict__ Bt,
    const float* __restrict__ bias, float* __restrict__ C,
    short* __restrict__ Cb, float* __restrict__ C2,
    const float* __restrict__ res, int K, int M,
    const int* __restrict__ offs, const int* __restrict__ tok_idx,
    const float* __restrict__ tok_gate)
{
    int e = (V >= 2) ? blockIdx.z : 0;
    const short* Bte = (V >= 2) ? Bt + (size_t)e * M * K : Bt;
    const float* be  = (V >= 2) ? bias + (size_t)e * M : bias;

    int row_lo, row_hi;
    if (V >= 2) {
        row_lo = offs[e] + blockIdx.y * 128;
        row_hi = offs[e + 1];
        if (row_lo >= row_hi) return;
    } else {
        row_lo = blockIdx.y * 128;
        row_hi = 1 << 30;
    }
    int col0 = blockIdx.x * 64;

    __shared__ short As[128 * 40];   // row stride 40 shorts (80B, 16B-aligned)
    __shared__ short Bs[64 * 40];

    int t = threadIdx.x;
    int sarow = t >> 1, sak = (t & 1) * 16;   // A staging: 2x16B per thread
    int sbrow = t >> 2, sbk = (t & 3) * 8;    // B staging: 1x16B per thread

    int  agrow = row_lo + sarow;
    bool aval  = true;
    int  asrc  = agrow;
    if (V == 2) { aval = agrow < row_hi; asrc = aval ? tok_idx[agrow] : 0; }
    if (V == 3) { aval = agrow < row_hi; if (!aval) asrc = 0; }
    const short* aptr = A   + (size_t)asrc * K + sak;
    const short* bptr = Bte + (size_t)(col0 + sbrow) * K + sbk;
    short* as_dst = &As[sarow * 40 + sak];
    short* bs_dst = &Bs[sbrow * 40 + sbk];

    int lane = t & 63, wave = t >> 6;
    int wm = (wave & 1) * 64, wn = (wave >> 1) * 32;
    int rin = lane & 15, quad = lane >> 4;

    floatx4 acc[4][2];
    #pragma unroll
    for (int i = 0; i < 4; ++i)
        #pragma unroll
        for (int j = 0; j < 2; ++j)
            acc[i][j] = (floatx4){0.f, 0.f, 0.f, 0.f};

    for (int k0 = 0; k0 < K; k0 += 32) {
        float4 z = make_float4(0.f, 0.f, 0.f, 0.f);
        float4 av0 = aval ? *(const float4*)(aptr + k0)     : z;
        float4 av1 = aval ? *(const float4*)(aptr + k0 + 8) : z;
        float4 bv  = *(const float4*)(bptr + k0);
        __syncthreads();   // WAR vs previous iteration's fragment reads
        *(float4*)(as_dst)     = av0;
        *(float4*)(as_dst + 8) = av1;
        *(float4*)(bs_dst)     = bv;
        __syncthreads();
        bf16x8 af[4], bfr[2];
        #pragma unroll
        for (int i = 0; i < 4; ++i)
            af[i] = *(const bf16x8*)&As[(wm + i * 16 + rin) * 40 + quad * 8];
        #pragma unroll
        for (int j = 0; j < 2; ++j)
            bfr[j] = *(const bf16x8*)&Bs[(wn + j * 16 + rin) * 40 + quad * 8];
        #pragma unroll
        for (int i = 0; i < 4; ++i)
            #pragma unroll
            for (int j = 0; j < 2; ++j)
                acc[i][j] = __builtin_amdgcn_mfma_f32_16x16x32_bf16(
                    af[i], bfr[j], acc[i][j], 0, 0, 0);
    }

    // Epilogue. C/D layout: col = lane&15, row = quad*4 + reg  [m89-verified]
    #pragma unroll
    for (int i = 0; i < 4; ++i) {
        #pragma unroll
        for (int j = 0; j < 2; ++j) {
            int cg = col0 + wn + j * 16 + rin;
            #pragma unroll
            for (int rr = 0; rr < 4; ++rr) {
                int rg = row_lo + wm + i * 16 + quad * 4 + rr;
                float val = acc[i][j][rr];
                if (V == 0) {
                    C[(size_t)rg * M + cg] = val + be[cg];
                } else if (V == 1) {
                    float o = val + be[cg] + res[(size_t)rg * M + cg];
                    C[(size_t)rg * M + cg]  = o;
                    C2[(size_t)rg * M + cg] = o;
                } else if (V == 2) {
                    if (rg < row_hi) {
                        float vb_ = val + be[cg];
                        Cb[(size_t)rg * M + cg] = f2bf(vb_ / (1.f + __expf(-vb_)));
                    }
                } else {
                    if (rg < row_hi)
                        atomicAdd(&C[(size_t)tok_idx[rg] * M + cg],
                                  tok_gate[rg] * (val + be[cg]));
                }
            }
        }
    }
}

// ---------------------------------------------------------------------------
// Sliding-window attention, lane-per-key. Block = (kv-head, 8-query tile):
// stage the 71-row K/V window in LDS (fp32, stride 132 -> conflict-optimal),
// each wave processes 8 (query,head) pairs; lane l owns key i-63+l.
// One 12-shuffle softmax per pair (vs 6 shuffles PER KEY before).
// ---------------------------------------------------------------------------
__global__ __launch_bounds__(256) void attn_kernel(
    const float* __restrict__ qkv, const float* __restrict__ sink_ptr,
    short* __restrict__ ao)
{
    __shared__ float Ks[WROWS * KVPAD];
    __shared__ float Vs[WROWS * KVPAD];
    __shared__ float Ps[4][64];

    int qblk = blockIdx.x;          // 0..S/QB-1
    int kvh  = blockIdx.y;          // 0..NKV-1
    int q0   = qblk * QB;
    int jbase = q0 - (WS_ - 1);

    int t = threadIdx.x;
    // --- stage K/V window ---
    {
        int c4 = (t & 31) * 4;
        for (int r = t >> 5; r < WROWS; r += 8) {
            int j = jbase + r;
            float4 kv4 = make_float4(0.f, 0.f, 0.f, 0.f);
            float4 vv4 = make_float4(0.f, 0.f, 0.f, 0.f);
            if (j >= 0) {
                const float* base = qkv + (size_t)j * QKV_M + kvh * HD;
                kv4 = *(const float4*)(base + KOFF - kvh * HD + kvh * HD + c4); // K
                kv4 = *(const float4*)(qkv + (size_t)j * QKV_M + KOFF + kvh * HD + c4);
                vv4 = *(const float4*)(qkv + (size_t)j * QKV_M + VOFF + kvh * HD + c4);
            }
            *(float4*)&Ks[r * KVPAD + c4] = kv4;
            *(float4*)&Vs[r * KVPAD + c4] = vv4;
        }
    }
    __syncthreads();

    int lane = t & 63, wave = t >> 6;
    float sink = sink_ptr[0];
    const float rscale = 0.08838834764831845f;  // 1/sqrt(128)

    #pragma unroll
    for (int it = 0; it < 8; ++it) {
        int pair = wave * 8 + it;        // 0..31
        int qi = pair >> 2;              // 0..7
        int h  = kvh * 4 + (pair & 3);   // global head
        int i  = q0 + qi;                // query index
        int j  = jbase + qi + lane;      // this lane's key

        // score: full 128-dim dot, K from LDS, q broadcast from global (L1/L2)
        const float* qrow = qkv + (size_t)i * QKV_M + h * HD;
        const float* krow = &Ks[(qi + lane) * KVPAD];
        float s0 = 0.f, s1 = 0.f, s2 = 0.f, s3 = 0.f;
        #pragma unroll
        for (int c = 0; c < 128; c += 16) {
            float4 q0v = *(const float4*)(qrow + c);
            float4 k0v = *(const float4*)(krow + c);
            float4 q1v = *(const float4*)(qrow + c + 4);
            float4 k1v = *(const float4*)(krow + c + 4);
            float4 q2v = *(const float4*)(qrow + c + 8);
            float4 k2v = *(const float4*)(krow + c + 8);
            float4 q3v = *(const float4*)(qrow + c + 12);
            float4 k3v = *(const float4*)(krow + c + 12);
            s0 += q0v.x*k0v.x + q0v.y*k0v.y + q0v.z*k0v.z + q0v.w*k0v.w;
            s1 += q1v.x*k1v.x + q1v.y*k1v.y + q1v.z*k1v.z + q1v.w*k1v.w;
            s2 += q2v.x*k2v.x + q2v.y*k2v.y + q2v.z*k2v.z + q2v.w*k2v.w;
            s3 += q3v.x*k3v.x + q3v.y*k3v.y + q3v.z*k3v.z + q3v.w*k3v.w;
        }
        float s = (j >= 0) ? (s0 + s1 + s2 + s3) * rscale : -1e30f;

        // softmax across 64 lanes + sink
        float m = s;
        #pragma unroll
        for (int off = 32; off; off >>= 1) m = fmaxf(m, __shfl_xor(m, off, 64));
        float mf = fmaxf(m, sink);
        float p  = __expf(s - mf);
        float ds = p;
        #pragma unroll
        for (int off = 32; off; off >>= 1) ds += __shfl_xor(ds, off, 64);
        float inv = 1.f / (ds + __expf(sink - mf));
        Ps[wave][lane] = p * inv;

        // PV: lane owns dims 2*lane, 2*lane+1; p broadcast from LDS
        float oxv = 0.f, oyv = 0.f;
        const float* vbase = &Vs[qi * KVPAD + 2 * lane];
        #pragma unroll
        for (int jj = 0; jj < 64; jj += 4) {
            float4 pj = *(const float4*)&Ps[wave][jj];
            float2 v0 = *(const float2*)(vbase + (jj + 0) * KVPAD);
            float2 v1 = *(const float2*)(vbase + (jj + 1) * KVPAD);
            float2 v2 = *(const float2*)(vbase + (jj + 2) * KVPAD);
            float2 v3 = *(const float2*)(vbase + (jj + 3) * KVPAD);
            oxv += pj.x*v0.x + pj.y*v1.x + pj.z*v2.x + pj.w*v3.x;
            oyv += pj.x*v0.y + pj.y*v1.y + pj.z*v2.y + pj.w*v3.y;
        }
        short2 o2; o2.x = f2bf(oxv); o2.y = f2bf(oyv);
        ((short2*)(ao + (size_t)i * D + h * HD))[lane] = o2;
    }
}

// ---------------------------------------------------------------------------
// Fused RMSNorm2 + router: block per token; normalized row kept in LDS,
// bf16 copy written for MoE; fp32 logits -> top-2, gates, histogram, colsum.
// ---------------------------------------------------------------------------
__global__ __launch_bounds__(256) void rms_router_kernel(
    const float* __restrict__ x1, const float* __restrict__ w,
    short* __restrict__ h2b,
    const float* __restrict__ rw, const float* __restrict__ rb,
    int* __restrict__ cnt, float* __restrict__ colsum,
    int* __restrict__ top_i, float* __restrict__ top_g)
{
    int tok = blockIdx.x, t = threadIdx.x;
    __shared__ float hrow[D];
    float4 v = ((const float4*)(x1 + (size_t)tok * D))[t];
    float ss = v.x*v.x + v.y*v.y + v.z*v.z + v.w*v.w;
    #pragma unroll
    for (int off = 32; off; off >>= 1) ss += __shfl_xor(ss, off, 64);
    __shared__ float red[4];
    if ((t & 63) == 0) red[t >> 6] = ss;
    __syncthreads();
    float total = red[0] + red[1] + red[2] + red[3];
    float scale = rsqrtf(total * (1.0f / (float)D) + 1e-6f);
    float4 wv = ((const float4*)w)[t];
    float4 o;
    o.x = v.x * scale * wv.x; o.y = v.y * scale * wv.y;
    o.z = v.z * scale * wv.z; o.w = v.w * scale * wv.w;
    ((float4*)hrow)[t] = o;
    short4 ob;
    ob.x = f2bf(o.x); ob.y = f2bf(o.y); ob.z = f2bf(o.z); ob.w = f2bf(o.w);
    ((short4*)(h2b + (size_t)tok * D))[t] = ob;
    __syncthreads();

    // router logits
    int e = t & 15, seg = t >> 4;
    float part = 0.f;
    int d0 = seg * 64;
    for (int d = d0; d < d0 + 64; ++d) part += hrow[d] * rw[d * E_ + e];
    __shared__ float lpart[256];
    lpart[t] = part;
    __syncthreads();
    __shared__ float logits[E_];
    if (t < E_) {
        float sl = 0.f;
        for (int sg = 0; sg < 16; ++sg) sl += lpart[sg * 16 + t];
        logits[t] = (sl + rb[t]) * 10.0f;   // /0.1
    }
    __syncthreads();
    __shared__ float sm[2];
    if (t == 0) {
        float mx = logits[0];
        for (int x = 1; x < E_; ++x) mx = fmaxf(mx, logits[x]);
        float ps = 0.f;
        for (int x = 0; x < E_; ++x) ps += __expf(logits[x] - mx);
        sm[0] = mx; sm[1] = ps;
        int i0 = 0; float v0 = logits[0];
        for (int x = 1; x < E_; ++x) if (logits[x] > v0) { v0 = logits[x]; i0 = x; }
        int i1 = -1; float v1 = -3.4e38f;
        for (int x = 0; x < E_; ++x) {
            if (x == i0) continue;
            if (logits[x] > v1) { v1 = logits[x]; i1 = x; }
        }
        float e1 = __expf(v1 - v0);
        float g0 = 1.f / (1.f + e1);
        float g1 = e1 * g0;
        top_i[tok * 2 + 0] = i0; top_g[tok * 2 + 0] = g0;
        top_i[tok * 2 + 1] = i1; top_g[tok * 2 + 1] = g1;
        atomicAdd(&cnt[i0], 1);
        atomicAdd(&cnt[i1], 1);
    }
    __syncthreads();
    if (t < E_) atomicAdd(&colsum[t], __expf(logits[t] - sm[0]) / sm[1]);
}

__global__ void offsets_kernel(const int* __restrict__ cnt, int* __restrict__ offs,
                               int* __restrict__ cursor,
                               const float* __restrict__ colsum,
                               float* __restrict__ aux_out)
{
    if (threadIdx.x == 0) {
        int acc = 0;
        for (int e = 0; e < E_; ++e) { offs[e] = acc; cursor[e] = acc; acc += cnt[e]; }
        offs[E_] = acc;
        float s = 0.f;
        for (int e = 0; e < E_; ++e) s += colsum[e] * colsum[e];
        *aux_out = s / (float)E_ * 1e-5f;
    }
}

__global__ __launch_bounds__(256) void scatter_kernel(
    const int* __restrict__ top_i, const float* __restrict__ top_g,
    int* __restrict__ cursor, int* __restrict__ tok_idx,
    float* __restrict__ tok_gate)
{
    int tok = blockIdx.x * 256 + threadIdx.x;
    if (tok >= NTOK) return;
    for (int s = 0; s < TOPK; ++s) {
        int e = top_i[tok * 2 + s];
        int pos = atomicAdd(&cursor[e], 1);
        tok_idx[pos]  = tok;
        tok_gate[pos] = top_g[tok * 2 + s];
    }
}

// ---------------------------------------------------------------------------
extern "C" void kernel_launch(void* const* d_in, const int* in_sizes, int n_in,
                              void* d_out, int out_size, void* d_ws, size_t ws_size,
                              hipStream_t stream)
{
    const float* x        = (const float*)d_in[0];
    const float* norm1_w  = (const float*)d_in[1];
    const float* wq       = (const float*)d_in[2];
    const float* bq       = (const float*)d_in[3];
    const float* wk       = (const float*)d_in[4];
    const float* bk       = (const float*)d_in[5];
    const float* wv       = (const float*)d_in[6];
    const float* bv       = (const float*)d_in[7];
    const float* wo       = (const float*)d_in[8];
    const float* bo       = (const float*)d_in[9];
    const float* sink     = (const float*)d_in[10];
    const float* norm2_w  = (const float*)d_in[11];
    const float* router_w = (const float*)d_in[12];
    const float* router_b = (const float*)d_in[13];
    const float* w1       = (const float*)d_in[14];
    const float* b1       = (const float*)d_in[15];
    const float* w2       = (const float*)d_in[16];
    const float* b2       = (const float*)d_in[17];
    float* out = (float*)d_out;

    // workspace layout
    char* w = (char*)d_ws;
    auto alloc = [&](size_t bytes) {
        char* p = w; w += (bytes + 255) & ~255ull; return p;
    };
    short* wqkvT = (short*)alloc((size_t)QKV_M * D * 2);       // [1536][1024]
    short* woT   = (short*)alloc((size_t)D * D * 2);           // [1024][1024]
    short* w1T   = (short*)alloc((size_t)E_ * HDIM * D * 2);   // [16][512][1024]
    short* w2T   = (short*)alloc((size_t)E_ * D * HDIM * 2);   // [16][1024][512]
    float* bqkv  = (float*)alloc(QKV_M * 4);
    short* h_bf  = (short*)alloc((size_t)S * D * 2);
    float* qkv   = (float*)alloc((size_t)S * QKV_M * 4);
    float* x1    = (float*)alloc((size_t)S * D * 4);
    short* h2b   = (short*)alloc((size_t)S * D * 2);
    int*   cnt      = (int*)alloc(32 * 4);   // cnt[16] + colsum[16] contiguous
    float* colsum   = (float*)(cnt + 16);
    int*   offs     = (int*)alloc(17 * 4);
    int*   cursor   = (int*)alloc(16 * 4);
    int*   top_i    = (int*)alloc((size_t)NSLOT * 4);
    float* top_g    = (float*)alloc((size_t)NSLOT * 4);
    int*   tok_idx  = (int*)alloc((size_t)NSLOT * 4);
    float* tok_gate = (float*)alloc((size_t)NSLOT * 4);
    // aliases (lifetimes don't overlap):
    short* ao_bf = h_bf;          // h_bf dead after QKV GEMM; attn writes ao after
    short* hmid  = (short*)qkv;   // qkv dead after attention; MoE1 writes hmid after

    hipMemsetAsync(cnt, 0, 32 * 4, stream);

    // 0) all weight prep in one launch
    tconv_all<<<18950, 256, 0, stream>>>(wq, wk, wv, wo, w1, w2, bq, bk, bv,
                                         wqkvT, woT, w1T, w2T, bqkv);

    // 1) h = rmsnorm(x) -> bf16
    rmsnorm_kernel<<<S, 256, 0, stream>>>(x, norm1_w, h_bf);

    // 2) fused QKV: qkv = h @ [wq|wk|wv] + [bq|bk|bv]   (384 blocks)
    mgemm<0><<<dim3(QKV_M / 64, S / 128), 256, 0, stream>>>(
        h_bf, wqkvT, bqkv, qkv, nullptr, nullptr, nullptr, D, QKV_M,
        nullptr, nullptr, nullptr);

    // 3) attention -> bf16 ao   (512 blocks, 2/CU)
    attn_kernel<<<dim3(S / QB, NKV), 256, 0, stream>>>(qkv, sink, ao_bf);

    // 4) x1 = x + ao@wo + bo  (also seeds d_out; 256 blocks)
    mgemm<1><<<dim3(D / 64, S / 128), 256, 0, stream>>>(
        ao_bf, woT, bo, x1, nullptr, out, x, D, D,
        nullptr, nullptr, nullptr);

    // 5+6) fused rmsnorm2 + router
    rms_router_kernel<<<NTOK, 256, 0, stream>>>(x1, norm2_w, h2b,
                                                router_w, router_b,
                                                cnt, colsum, top_i, top_g);

    // 7) offsets + aux loss -> out[S*D]
    offsets_kernel<<<1, 64, 0, stream>>>(cnt, offs, cursor, colsum,
                                         out + (size_t)S * D);

    // 8) scatter token slots expert-contiguously
    scatter_kernel<<<(NTOK + 255) / 256, 256, 0, stream>>>(
        top_i, top_g, cursor, tok_idx, tok_gate);

    // 9) MoE GEMM1: hmid = silu(gather(h2b) @ w1[e] + b1[e]) -> bf16
    mgemm<2><<<dim3(HDIM / 64, NSLOT / 128, E_), 256, 0, stream>>>(
        h2b, w1T, b1, nullptr, hmid, nullptr, nullptr, D, HDIM,
        offs, tok_idx, tok_gate);

    // 10) MoE GEMM2: out[token] += gate * (hmid @ w2[e] + b2[e])
    mgemm<3><<<dim3(D / 64, NSLOT / 128, E_), 256, 0, stream>>>(
        hmid, w2T, b2, out, nullptr, nullptr, nullptr, HDIM, D,
        offs, tok_idx, tok_gate);
}

// Round 5
// 420.583 us; speedup vs baseline: 2.1016x; 1.1466x over previous
//
#include <hip/hip_runtime.h>
#include <hip/hip_bf16.h>

// Problem constants
#define S     2048
#define D     1024
#define NH    8
#define NKV   2
#define HD    128
#define WS_   64
#define E_    16
#define HDIM  512
#define TOPK  2
#define NTOK  S
#define NSLOT (S*TOPK)         // 4096
#define QKV_M (D + 2*NKV*HD)   // 1536 fused q|k|v columns
#define KOFF  D                // 1024
#define VOFF  (D + NKV*HD)     // 1280
#define QB    8                // queries per attention block
#define WROWS (QB + WS_ - 1)   // 71 key rows per window
#define KPITCH 73              // KT key pitch (float4 units): stride 73*16B -> reads contiguous, writes 4-way max
#define VPADF  132             // Vs row stride in floats (132%32==4; b64 reads contiguous)

typedef __attribute__((ext_vector_type(8))) short bf16x8;
typedef __attribute__((ext_vector_type(4))) float floatx4;

__device__ inline short f2bf(float f) {
    __hip_bfloat16 b = __float2bfloat16(f);
    return *reinterpret_cast<short*>(&b);
}

// ---------------------------------------------------------------------------
// All weight prep in ONE launch: 6 transpose+convert regions + bias concat.
// ---------------------------------------------------------------------------
__global__ __launch_bounds__(256) void tconv_all(
    const float* __restrict__ wq, const float* __restrict__ wk,
    const float* __restrict__ wv, const float* __restrict__ wo,
    const float* __restrict__ w1, const float* __restrict__ w2,
    const float* __restrict__ bq, const float* __restrict__ bk,
    const float* __restrict__ bv,
    short* __restrict__ wqkvT, short* __restrict__ woT,
    short* __restrict__ w1T, short* __restrict__ w2T,
    float* __restrict__ bqkv)
{
    int id = blockIdx.x;
    if (id >= 18944) {                       // 6 bias-concat blocks
        int t = (id - 18944) * 256 + threadIdx.x;
        if (t < D) bqkv[t] = bq[t];
        else if (t < VOFF) bqkv[t] = bk[t - D];
        else bqkv[t] = bv[t - VOFF];
        return;
    }
    const float* in; short* outp; int K, M, mx, ky;
    if (id < 1024)      { in = wq; outp = wqkvT;                  K = D; M = D;   int l = id;        mx = l & 31; ky = l >> 5; }
    else if (id < 1280) { in = wk; outp = wqkvT + (size_t)KOFF*D; K = D; M = 256; int l = id - 1024; mx = l & 7;  ky = l >> 3; }
    else if (id < 1536) { in = wv; outp = wqkvT + (size_t)VOFF*D; K = D; M = 256; int l = id - 1280; mx = l & 7;  ky = l >> 3; }
    else if (id < 2560) { in = wo; outp = woT;                    K = D; M = D;   int l = id - 1536; mx = l & 31; ky = l >> 5; }
    else if (id < 10752){ int l = id - 2560;  int e = l >> 9; int r = l & 511;
                          in = w1 + (size_t)e * D * HDIM; outp = w1T + (size_t)e * D * HDIM;
                          K = D; M = HDIM; mx = r & 15; ky = r >> 4; }
    else                { int l = id - 10752; int e = l >> 9; int r = l & 511;
                          in = w2 + (size_t)e * D * HDIM; outp = w2T + (size_t)e * D * HDIM;
                          K = HDIM; M = D; mx = r & 31; ky = r >> 5; }
    __shared__ float tile[32][33];
    int t = threadIdx.x, r = t >> 3, c4 = (t & 7) * 4;
    int k0 = ky * 32, m0 = mx * 32;
    float4 v = *(const float4*)&in[(size_t)(k0 + r) * M + m0 + c4];
    tile[r][c4 + 0] = v.x; tile[r][c4 + 1] = v.y;
    tile[r][c4 + 2] = v.z; tile[r][c4 + 3] = v.w;
    __syncthreads();
    short4 o;
    o.x = f2bf(tile[c4 + 0][r]);
    o.y = f2bf(tile[c4 + 1][r]);
    o.z = f2bf(tile[c4 + 2][r]);
    o.w = f2bf(tile[c4 + 3][r]);
    *(short4*)&outp[(size_t)(m0 + r) * K + k0 + c4] = o;
}

// ---------------------------------------------------------------------------
// RMSNorm (attention pre-norm): fp32 in -> bf16 out
// ---------------------------------------------------------------------------
__global__ __launch_bounds__(256) void rmsnorm_kernel(
    const float* __restrict__ x, const float* __restrict__ w,
    short* __restrict__ outb)
{
    int row = blockIdx.x, t = threadIdx.x;
    float4 v = ((const float4*)(x + (size_t)row * D))[t];
    float ss = v.x*v.x + v.y*v.y + v.z*v.z + v.w*v.w;
    #pragma unroll
    for (int off = 32; off; off >>= 1) ss += __shfl_xor(ss, off, 64);
    __shared__ float red[4];
    if ((t & 63) == 0) red[t >> 6] = ss;
    __syncthreads();
    float total = red[0] + red[1] + red[2] + red[3];
    float scale = rsqrtf(total * (1.0f / (float)D) + 1e-6f);
    float4 wv = ((const float4*)w)[t];
    short4 ob;
    ob.x = f2bf(v.x * scale * wv.x); ob.y = f2bf(v.y * scale * wv.y);
    ob.z = f2bf(v.z * scale * wv.z); ob.w = f2bf(v.w * scale * wv.w);
    ((short4*)(outb + (size_t)row * D))[t] = ob;
}

// ---------------------------------------------------------------------------
// bf16 MFMA GEMM: C[N,M] = A[N,K](bf16) @ Bt[M,K]^T(bf16) + bias
// 128x64 block tile, BK=32, 4 waves (2x2): each wave 64 rows x 32 cols.
// V=0: C fp32 (fused QKV)   V=1: C = acc+bias+res (WO + residual -> x1)
// V=2: MoE1 gather+silu->bf16   V=3: MoE2 gate-scaled store to slot buffer
// ---------------------------------------------------------------------------
template <int V>
__global__ __launch_bounds__(256) void mgemm(
    const short* __restrict__ A, const short* __restrict__ Bt,
    const float* __restrict__ bias, float* __restrict__ C,
    short* __restrict__ Cb, const float* __restrict__ res, int K, int M,
    const int* __restrict__ offs, const int* __restrict__ tok_idx,
    const float* __restrict__ tok_gate)
{
    int e = (V >= 2) ? blockIdx.z : 0;
    const short* Bte = (V >= 2) ? Bt + (size_t)e * M * K : Bt;
    const float* be  = (V >= 2) ? bias + (size_t)e * M : bias;

    int row_lo, row_hi;
    if (V >= 2) {
        row_lo = offs[e] + blockIdx.y * 128;
        row_hi = offs[e + 1];
        if (row_lo >= row_hi) return;
    } else {
        row_lo = blockIdx.y * 128;
        row_hi = 1 << 30;
    }
    int col0 = blockIdx.x * 64;

    __shared__ short As[128 * 40];   // row stride 40 shorts (80B, 16B-aligned)
    __shared__ short Bs[64 * 40];

    int t = threadIdx.x;
    int sarow = t >> 1, sak = (t & 1) * 16;   // A staging: 2x16B per thread
    int sbrow = t >> 2, sbk = (t & 3) * 8;    // B staging: 1x16B per thread

    int  agrow = row_lo + sarow;
    bool aval  = true;
    int  asrc  = agrow;
    if (V == 2) { aval = agrow < row_hi; asrc = aval ? tok_idx[agrow] : 0; }
    if (V == 3) { aval = agrow < row_hi; if (!aval) asrc = 0; }
    const short* aptr = A   + (size_t)asrc * K + sak;
    const short* bptr = Bte + (size_t)(col0 + sbrow) * K + sbk;
    short* as_dst = &As[sarow * 40 + sak];
    short* bs_dst = &Bs[sbrow * 40 + sbk];

    int lane = t & 63, wave = t >> 6;
    int wm = (wave & 1) * 64, wn = (wave >> 1) * 32;
    int rin = lane & 15, quad = lane >> 4;

    floatx4 acc[4][2];
    #pragma unroll
    for (int i = 0; i < 4; ++i)
        #pragma unroll
        for (int j = 0; j < 2; ++j)
            acc[i][j] = (floatx4){0.f, 0.f, 0.f, 0.f};

    for (int k0 = 0; k0 < K; k0 += 32) {
        float4 z = make_float4(0.f, 0.f, 0.f, 0.f);
        float4 av0 = aval ? *(const float4*)(aptr + k0)     : z;
        float4 av1 = aval ? *(const float4*)(aptr + k0 + 8) : z;
        float4 bv  = *(const float4*)(bptr + k0);
        __syncthreads();   // WAR vs previous iteration's fragment reads
        *(float4*)(as_dst)     = av0;
        *(float4*)(as_dst + 8) = av1;
        *(float4*)(bs_dst)     = bv;
        __syncthreads();
        bf16x8 af[4], bfr[2];
        #pragma unroll
        for (int i = 0; i < 4; ++i)
            af[i] = *(const bf16x8*)&As[(wm + i * 16 + rin) * 40 + quad * 8];
        #pragma unroll
        for (int j = 0; j < 2; ++j)
            bfr[j] = *(const bf16x8*)&Bs[(wn + j * 16 + rin) * 40 + quad * 8];
        #pragma unroll
        for (int i = 0; i < 4; ++i)
            #pragma unroll
            for (int j = 0; j < 2; ++j)
                acc[i][j] = __builtin_amdgcn_mfma_f32_16x16x32_bf16(
                    af[i], bfr[j], acc[i][j], 0, 0, 0);
    }

    // Epilogue. C/D layout: col = lane&15, row = quad*4 + reg  [m89-verified]
    #pragma unroll
    for (int i = 0; i < 4; ++i) {
        #pragma unroll
        for (int j = 0; j < 2; ++j) {
            int cg = col0 + wn + j * 16 + rin;
            #pragma unroll
            for (int rr = 0; rr < 4; ++rr) {
                int rg = row_lo + wm + i * 16 + quad * 4 + rr;
                float val = acc[i][j][rr];
                if (V == 0) {
                    C[(size_t)rg * M + cg] = val + be[cg];
                } else if (V == 1) {
                    C[(size_t)rg * M + cg] = val + be[cg] + res[(size_t)rg * M + cg];
                } else if (V == 2) {
                    if (rg < row_hi) {
                        float vb_ = val + be[cg];
                        Cb[(size_t)rg * M + cg] = f2bf(vb_ / (1.f + __expf(-vb_)));
                    }
                } else {
                    if (rg < row_hi)
                        C[(size_t)rg * M + cg] = tok_gate[rg] * (val + be[cg]);
                }
            }
        }
    }
}

// ---------------------------------------------------------------------------
// Sliding-window attention — fp32 math (matches R3-passing numerics),
// conflict-free LDS layout:
//   KT: K transposed [c4g=32][key<=KPITCH] of float4
//       -> score reads: lane l reads float4 at key=qi+l -> contiguous b128, 0-conflict
//   Vs: [key][dim] fp32, row stride VPADF -> PV b64 reads contiguous, 2-way=free
//   Q:  read from global fp32, wave-uniform address -> L1 broadcast (R3 style)
//   Ps4: per-wave [key] float4 = probs of 4 heads (uniform broadcast reads)
// Each wave: 2 queries x 4 heads; K/V LDS traffic shared across the 4 heads.
// LDS = 37376 + 37488 + 4096 = 78960 B -> 2 blocks/CU.
// ---------------------------------------------------------------------------
__global__ __launch_bounds__(256) void attn_kernel(
    const float* __restrict__ qkv, const float* __restrict__ sink_ptr,
    short* __restrict__ ao)
{
    __shared__ __align__(16) float KT[32 * KPITCH * 4];
    __shared__ __align__(16) float Vs[WROWS * VPADF];
    __shared__ __align__(16) float Ps4[4][64][4];

    int qblk = blockIdx.x;          // 0..S/QB-1
    int kvh  = blockIdx.y;          // 0..NKV-1
    int q0   = qblk * QB;
    int jbase = q0 - (WS_ - 1);

    int t = threadIdx.x;
    int c4 = (t & 31) * 4, c4g = t & 31;
    // --- stage K (transposed) and V, fp32 ---
    for (int r = t >> 5; r < WROWS; r += 8) {
        int j = jbase + r;
        float4 kv4 = make_float4(0.f, 0.f, 0.f, 0.f);
        float4 vv4 = make_float4(0.f, 0.f, 0.f, 0.f);
        if (j >= 0) {
            kv4 = *(const float4*)(qkv + (size_t)j * QKV_M + KOFF + kvh * HD + c4);
            vv4 = *(const float4*)(qkv + (size_t)j * QKV_M + VOFF + kvh * HD + c4);
        }
        *(float4*)&KT[(c4g * KPITCH + r) * 4] = kv4;
        *(float4*)&Vs[r * VPADF + c4] = vv4;
    }
    __syncthreads();

    int lane = t & 63, wv = t >> 6;
    float sink = sink_ptr[0];
    const float rscale = 0.08838834764831845f;  // 1/sqrt(128)

    #pragma unroll
    for (int g = 0; g < 2; ++g) {
        int qi = wv * 2 + g;
        int i  = q0 + qi;
        bool valid = (jbase + qi + lane) >= 0;   // this lane's key j >= 0

        // ---- scores: 4 heads share each K read; q from global (uniform) ----
        float sc[4] = {0.f, 0.f, 0.f, 0.f};
        const float* qbase = qkv + (size_t)i * QKV_M + (kvh * 4) * HD;
        #pragma unroll
        for (int c = 0; c < 32; ++c) {
            float4 kx = *(const float4*)&KT[(c * KPITCH + qi + lane) * 4];
            #pragma unroll
            for (int hh = 0; hh < 4; ++hh) {
                float4 q4 = *(const float4*)(qbase + hh * HD + c * 4);
                sc[hh] += q4.x*kx.x + q4.y*kx.y + q4.z*kx.z + q4.w*kx.w;
            }
        }

        // ---- softmax per head across 64 lanes + sink ----
        float pn[4];
        #pragma unroll
        for (int hh = 0; hh < 4; ++hh) {
            float s = valid ? sc[hh] * rscale : -1e30f;
            float m = s;
            #pragma unroll
            for (int off = 32; off; off >>= 1) m = fmaxf(m, __shfl_xor(m, off, 64));
            float mf = fmaxf(m, sink);
            float p  = __expf(s - mf);
            float ds = p;
            #pragma unroll
            for (int off = 32; off; off >>= 1) ds += __shfl_xor(ds, off, 64);
            pn[hh] = p / (ds + __expf(sink - mf));
        }
        *(float4*)&Ps4[wv][lane][0] = make_float4(pn[0], pn[1], pn[2], pn[3]);

        // ---- PV: lane owns dims (2*lane, 2*lane+1); V read shared by 4 heads
        float o0=0,o1=0,o2=0,o3=0,o4=0,o5=0,o6=0,o7=0;
        const float* vp = &Vs[qi * VPADF + 2 * lane];
        #pragma unroll
        for (int jj = 0; jj < 64; ++jj) {
            float4 p4 = *(const float4*)&Ps4[wv][jj][0];   // uniform broadcast
            float2 vv = *(const float2*)(vp + jj * VPADF);
            o0 += p4.x * vv.x; o1 += p4.x * vv.y;
            o2 += p4.y * vv.x; o3 += p4.y * vv.y;
            o4 += p4.z * vv.x; o5 += p4.z * vv.y;
            o6 += p4.w * vv.x; o7 += p4.w * vv.y;
        }
        short2 r0; r0.x = f2bf(o0); r0.y = f2bf(o1);
        short2 r1; r1.x = f2bf(o2); r1.y = f2bf(o3);
        short2 r2; r2.x = f2bf(o4); r2.y = f2bf(o5);
        short2 r3; r3.x = f2bf(o6); r3.y = f2bf(o7);
        ((short2*)(ao + (size_t)i * D + (kvh * 4 + 0) * HD))[lane] = r0;
        ((short2*)(ao + (size_t)i * D + (kvh * 4 + 1) * HD))[lane] = r1;
        ((short2*)(ao + (size_t)i * D + (kvh * 4 + 2) * HD))[lane] = r2;
        ((short2*)(ao + (size_t)i * D + (kvh * 4 + 3) * HD))[lane] = r3;
    }
}

// ---------------------------------------------------------------------------
// Fused RMSNorm2 + router
// ---------------------------------------------------------------------------
__global__ __launch_bounds__(256) void rms_router_kernel(
    const float* __restrict__ x1, const float* __restrict__ w,
    short* __restrict__ h2b,
    const float* __restrict__ rw, const float* __restrict__ rb,
    int* __restrict__ cnt, float* __restrict__ colsum,
    int* __restrict__ top_i, float* __restrict__ top_g)
{
    int tok = blockIdx.x, t = threadIdx.x;
    __shared__ float hrow[D];
    float4 v = ((const float4*)(x1 + (size_t)tok * D))[t];
    float ss = v.x*v.x + v.y*v.y + v.z*v.z + v.w*v.w;
    #pragma unroll
    for (int off = 32; off; off >>= 1) ss += __shfl_xor(ss, off, 64);
    __shared__ float red[4];
    if ((t & 63) == 0) red[t >> 6] = ss;
    __syncthreads();
    float total = red[0] + red[1] + red[2] + red[3];
    float scale = rsqrtf(total * (1.0f / (float)D) + 1e-6f);
    float4 wv = ((const float4*)w)[t];
    float4 o;
    o.x = v.x * scale * wv.x; o.y = v.y * scale * wv.y;
    o.z = v.z * scale * wv.z; o.w = v.w * scale * wv.w;
    ((float4*)hrow)[t] = o;
    short4 ob;
    ob.x = f2bf(o.x); ob.y = f2bf(o.y); ob.z = f2bf(o.z); ob.w = f2bf(o.w);
    ((short4*)(h2b + (size_t)tok * D))[t] = ob;
    __syncthreads();

    int e = t & 15, seg = t >> 4;
    float part = 0.f;
    int d0 = seg * 64;
    for (int d = d0; d < d0 + 64; ++d) part += hrow[d] * rw[d * E_ + e];
    __shared__ float lpart[256];
    lpart[t] = part;
    __syncthreads();
    __shared__ float logits[E_];
    if (t < E_) {
        float sl = 0.f;
        for (int sg = 0; sg < 16; ++sg) sl += lpart[sg * 16 + t];
        logits[t] = (sl + rb[t]) * 10.0f;   // /0.1
    }
    __syncthreads();
    __shared__ float sm[2];
    if (t == 0) {
        float mx = logits[0];
        for (int x = 1; x < E_; ++x) mx = fmaxf(mx, logits[x]);
        float ps = 0.f;
        for (int x = 0; x < E_; ++x) ps += __expf(logits[x] - mx);
        sm[0] = mx; sm[1] = ps;
        int i0 = 0; float v0 = logits[0];
        for (int x = 1; x < E_; ++x) if (logits[x] > v0) { v0 = logits[x]; i0 = x; }
        int i1 = -1; float v1 = -3.4e38f;
        for (int x = 0; x < E_; ++x) {
            if (x == i0) continue;
            if (logits[x] > v1) { v1 = logits[x]; i1 = x; }
        }
        float e1 = __expf(v1 - v0);
        float g0 = 1.f / (1.f + e1);
        float g1 = e1 * g0;
        top_i[tok * 2 + 0] = i0; top_g[tok * 2 + 0] = g0;
        top_i[tok * 2 + 1] = i1; top_g[tok * 2 + 1] = g1;
        atomicAdd(&cnt[i0], 1);
        atomicAdd(&cnt[i1], 1);
    }
    __syncthreads();
    if (t < E_) atomicAdd(&colsum[t], __expf(logits[t] - sm[0]) / sm[1]);
}

__global__ void offsets_kernel(const int* __restrict__ cnt, int* __restrict__ offs,
                               int* __restrict__ cursor,
                               const float* __restrict__ colsum,
                               float* __restrict__ aux_out)
{
    if (threadIdx.x == 0) {
        int acc = 0;
        for (int e = 0; e < E_; ++e) { offs[e] = acc; cursor[e] = acc; acc += cnt[e]; }
        offs[E_] = acc;
        float s = 0.f;
        for (int e = 0; e < E_; ++e) s += colsum[e] * colsum[e];
        *aux_out = s / (float)E_ * 1e-5f;
    }
}

__global__ __launch_bounds__(256) void scatter_kernel(
    const int* __restrict__ top_i, const float* __restrict__ top_g,
    int* __restrict__ cursor, int* __restrict__ tok_idx,
    float* __restrict__ tok_gate, int* __restrict__ slot_of)
{
    int tok = blockIdx.x * 256 + threadIdx.x;
    if (tok >= NTOK) return;
    for (int s = 0; s < TOPK; ++s) {
        int e = top_i[tok * 2 + s];
        int pos = atomicAdd(&cursor[e], 1);
        tok_idx[pos]  = tok;
        tok_gate[pos] = top_g[tok * 2 + s];
        slot_of[tok * 2 + s] = pos;
    }
}

// out[tok] = x1[tok] + y[slot0] + y[slot1]
__global__ __launch_bounds__(256) void combine_kernel(
    const float* __restrict__ x1, const float* __restrict__ y,
    const int* __restrict__ slot_of, float* __restrict__ out)
{
    int tok = blockIdx.x, t = threadIdx.x;
    int s0 = slot_of[tok * 2], s1 = slot_of[tok * 2 + 1];
    float4 a = ((const float4*)(x1 + (size_t)tok * D))[t];
    float4 b = ((const float4*)(y + (size_t)s0 * D))[t];
    float4 c = ((const float4*)(y + (size_t)s1 * D))[t];
    float4 o;
    o.x = a.x + b.x + c.x; o.y = a.y + b.y + c.y;
    o.z = a.z + b.z + c.z; o.w = a.w + b.w + c.w;
    ((float4*)(out + (size_t)tok * D))[t] = o;
}

// ---------------------------------------------------------------------------
extern "C" void kernel_launch(void* const* d_in, const int* in_sizes, int n_in,
                              void* d_out, int out_size, void* d_ws, size_t ws_size,
                              hipStream_t stream)
{
    const float* x        = (const float*)d_in[0];
    const float* norm1_w  = (const float*)d_in[1];
    const float* wq       = (const float*)d_in[2];
    const float* bq       = (const float*)d_in[3];
    const float* wk       = (const float*)d_in[4];
    const float* bk       = (const float*)d_in[5];
    const float* wv       = (const float*)d_in[6];
    const float* bv       = (const float*)d_in[7];
    const float* wo       = (const float*)d_in[8];
    const float* bo       = (const float*)d_in[9];
    const float* sink     = (const float*)d_in[10];
    const float* norm2_w  = (const float*)d_in[11];
    const float* router_w = (const float*)d_in[12];
    const float* router_b = (const float*)d_in[13];
    const float* w1       = (const float*)d_in[14];
    const float* b1       = (const float*)d_in[15];
    const float* w2       = (const float*)d_in[16];
    const float* b2       = (const float*)d_in[17];
    float* out = (float*)d_out;

    // workspace layout
    char* w = (char*)d_ws;
    auto alloc = [&](size_t bytes) {
        char* p = w; w += (bytes + 255) & ~255ull; return p;
    };
    short* wqkvT = (short*)alloc((size_t)QKV_M * D * 2);       // [1536][1024]
    short* woT   = (short*)alloc((size_t)D * D * 2);           // [1024][1024]
    short* w1T   = (short*)alloc((size_t)E_ * HDIM * D * 2);   // [16][512][1024]
    short* w2T   = (short*)alloc((size_t)E_ * D * HDIM * 2);   // [16][1024][512]
    float* bqkv  = (float*)alloc(QKV_M * 4);
    short* h_bf  = (short*)alloc((size_t)S * D * 2);
    float* qkv   = (float*)alloc((size_t)S * QKV_M * 4);
    float* x1    = (float*)alloc((size_t)S * D * 4);
    short* h2b   = (short*)alloc((size_t)S * D * 2);
    float* yslot = (float*)alloc((size_t)NSLOT * D * 4);       // 16.8 MB
    int*   cnt      = (int*)alloc(32 * 4);   // cnt[16] + colsum[16]
    float* colsum   = (float*)(cnt + 16);
    int*   offs     = (int*)alloc(17 * 4);
    int*   cursor   = (int*)alloc(16 * 4);
    int*   top_i    = (int*)alloc((size_t)NSLOT * 4);
    float* top_g    = (float*)alloc((size_t)NSLOT * 4);
    int*   tok_idx  = (int*)alloc((size_t)NSLOT * 4);
    float* tok_gate = (float*)alloc((size_t)NSLOT * 4);
    int*   slot_of  = (int*)alloc((size_t)NSLOT * 4);
    // aliases (lifetimes don't overlap):
    short* ao_bf = h_bf;          // h_bf dead after QKV GEMM
    short* hmid  = (short*)qkv;   // qkv dead after attention

    hipMemsetAsync(cnt, 0, 32 * 4, stream);

    // 0) all weight prep in one launch
    tconv_all<<<18950, 256, 0, stream>>>(wq, wk, wv, wo, w1, w2, bq, bk, bv,
                                         wqkvT, woT, w1T, w2T, bqkv);

    // 1) h = rmsnorm(x) -> bf16
    rmsnorm_kernel<<<S, 256, 0, stream>>>(x, norm1_w, h_bf);

    // 2) fused QKV: qkv = h @ [wq|wk|wv] + [bq|bk|bv]   (384 blocks)
    mgemm<0><<<dim3(QKV_M / 64, S / 128), 256, 0, stream>>>(
        h_bf, wqkvT, bqkv, qkv, nullptr, nullptr, D, QKV_M,
        nullptr, nullptr, nullptr);

    // 3) attention -> bf16 ao   (512 blocks)
    attn_kernel<<<dim3(S / QB, NKV), 256, 0, stream>>>(qkv, sink, ao_bf);

    // 4) x1 = x + ao@wo + bo
    mgemm<1><<<dim3(D / 64, S / 128), 256, 0, stream>>>(
        ao_bf, woT, bo, x1, nullptr, x, D, D,
        nullptr, nullptr, nullptr);

    // 5+6) fused rmsnorm2 + router
    rms_router_kernel<<<NTOK, 256, 0, stream>>>(x1, norm2_w, h2b,
                                                router_w, router_b,
                                                cnt, colsum, top_i, top_g);

    // 7) offsets + aux loss -> out[S*D]
    offsets_kernel<<<1, 64, 0, stream>>>(cnt, offs, cursor, colsum,
                                         out + (size_t)S * D);

    // 8) scatter token slots expert-contiguously (+ inverse slot map)
    scatter_kernel<<<(NTOK + 255) / 256, 256, 0, stream>>>(
        top_i, top_g, cursor, tok_idx, tok_gate, slot_of);

    // 9) MoE GEMM1: hmid = silu(gather(h2b) @ w1[e] + b1[e]) -> bf16
    mgemm<2><<<dim3(HDIM / 64, NSLOT / 128, E_), 256, 0, stream>>>(
        h2b, w1T, b1, nullptr, hmid, nullptr, D, HDIM,
        offs, tok_idx, tok_gate);

    // 10) MoE GEMM2: yslot[slot] = gate * (hmid @ w2[e] + b2[e])
    mgemm<3><<<dim3(D / 64, NSLOT / 128, E_), 256, 0, stream>>>(
        hmid, w2T, b2, yslot, nullptr, nullptr, HDIM, D,
        offs, tok_idx, tok_gate);

    // 11) out = x1 + yslot[slot0] + yslot[slot1]
    combine_kernel<<<NTOK, 256, 0, stream>>>(x1, yslot, slot_of, out);
}

// Round 6
// 358.785 us; speedup vs baseline: 2.4636x; 1.1722x over previous
//
#include <hip/hip_runtime.h>
#include <hip/hip_bf16.h>

// Problem constants
#define S     2048
#define D     1024
#define NH    8
#define NKV   2
#define HD    128
#define WS_   64
#define E_    16
#define HDIM  512
#define TOPK  2
#define NTOK  S
#define NSLOT (S*TOPK)         // 4096
#define QKV_M (D + 2*NKV*HD)   // 1536 fused q|k|v columns
#define KOFF  D                // 1024
#define VOFF  (D + NKV*HD)     // 1280
#define QB    8                // queries per attention block
#define WROWS (QB + WS_ - 1)   // 71 key rows per window
#define KPITCH 73              // KT key pitch (float4 units)
#define VPADF  132             // Vs row stride in floats

typedef __attribute__((ext_vector_type(8))) short bf16x8;
typedef __attribute__((ext_vector_type(4))) float floatx4;

__device__ inline short f2bf(float f) {
    __hip_bfloat16 b = __float2bfloat16(f);
    return *reinterpret_cast<short*>(&b);
}

// ---------------------------------------------------------------------------
// All weight prep in ONE launch: 6 transpose+convert regions + bias concat.
// ---------------------------------------------------------------------------
__global__ __launch_bounds__(256) void tconv_all(
    const float* __restrict__ wq, const float* __restrict__ wk,
    const float* __restrict__ wv, const float* __restrict__ wo,
    const float* __restrict__ w1, const float* __restrict__ w2,
    const float* __restrict__ bq, const float* __restrict__ bk,
    const float* __restrict__ bv,
    short* __restrict__ wqkvT, short* __restrict__ woT,
    short* __restrict__ w1T, short* __restrict__ w2T,
    float* __restrict__ bqkv)
{
    int id = blockIdx.x;
    if (id >= 18944) {                       // 6 bias-concat blocks
        int t = (id - 18944) * 256 + threadIdx.x;
        if (t < D) bqkv[t] = bq[t];
        else if (t < VOFF) bqkv[t] = bk[t - D];
        else bqkv[t] = bv[t - VOFF];
        return;
    }
    const float* in; short* outp; int K, M, mx, ky;
    if (id < 1024)      { in = wq; outp = wqkvT;                  K = D; M = D;   int l = id;        mx = l & 31; ky = l >> 5; }
    else if (id < 1280) { in = wk; outp = wqkvT + (size_t)KOFF*D; K = D; M = 256; int l = id - 1024; mx = l & 7;  ky = l >> 3; }
    else if (id < 1536) { in = wv; outp = wqkvT + (size_t)VOFF*D; K = D; M = 256; int l = id - 1280; mx = l & 7;  ky = l >> 3; }
    else if (id < 2560) { in = wo; outp = woT;                    K = D; M = D;   int l = id - 1536; mx = l & 31; ky = l >> 5; }
    else if (id < 10752){ int l = id - 2560;  int e = l >> 9; int r = l & 511;
                          in = w1 + (size_t)e * D * HDIM; outp = w1T + (size_t)e * D * HDIM;
                          K = D; M = HDIM; mx = r & 15; ky = r >> 4; }
    else                { int l = id - 10752; int e = l >> 9; int r = l & 511;
                          in = w2 + (size_t)e * D * HDIM; outp = w2T + (size_t)e * D * HDIM;
                          K = HDIM; M = D; mx = r & 31; ky = r >> 5; }
    __shared__ float tile[32][33];
    int t = threadIdx.x, r = t >> 3, c4 = (t & 7) * 4;
    int k0 = ky * 32, m0 = mx * 32;
    float4 v = *(const float4*)&in[(size_t)(k0 + r) * M + m0 + c4];
    tile[r][c4 + 0] = v.x; tile[r][c4 + 1] = v.y;
    tile[r][c4 + 2] = v.z; tile[r][c4 + 3] = v.w;
    __syncthreads();
    short4 o;
    o.x = f2bf(tile[c4 + 0][r]);
    o.y = f2bf(tile[c4 + 1][r]);
    o.z = f2bf(tile[c4 + 2][r]);
    o.w = f2bf(tile[c4 + 3][r]);
    *(short4*)&outp[(size_t)(m0 + r) * K + k0 + c4] = o;
}

// ---------------------------------------------------------------------------
// RMSNorm (attention pre-norm): fp32 in -> bf16 out
// ---------------------------------------------------------------------------
__global__ __launch_bounds__(256) void rmsnorm_kernel(
    const float* __restrict__ x, const float* __restrict__ w,
    short* __restrict__ outb)
{
    int row = blockIdx.x, t = threadIdx.x;
    float4 v = ((const float4*)(x + (size_t)row * D))[t];
    float ss = v.x*v.x + v.y*v.y + v.z*v.z + v.w*v.w;
    #pragma unroll
    for (int off = 32; off; off >>= 1) ss += __shfl_xor(ss, off, 64);
    __shared__ float red[4];
    if ((t & 63) == 0) red[t >> 6] = ss;
    __syncthreads();
    float total = red[0] + red[1] + red[2] + red[3];
    float scale = rsqrtf(total * (1.0f / (float)D) + 1e-6f);
    float4 wv = ((const float4*)w)[t];
    short4 ob;
    ob.x = f2bf(v.x * scale * wv.x); ob.y = f2bf(v.y * scale * wv.y);
    ob.z = f2bf(v.z * scale * wv.z); ob.w = f2bf(v.w * scale * wv.w);
    ((short4*)(outb + (size_t)row * D))[t] = ob;
}

// ---------------------------------------------------------------------------
// bf16 MFMA GEMM: C[N,M] = A[N,K](bf16) @ Bt[M,K]^T(bf16) + bias
// RT x 64 block tile, BK=32, 4 waves (2x2), software-pipelined K-loop
// (tile k+1 preloaded into VGPRs while tile k computes).
// RT=128 for dense (QKV/WO), RT=64 for MoE (2x the active blocks).
// V=0: C fp32 (fused QKV)   V=1: C = acc+bias+res (WO + residual -> x1)
// V=2: MoE1 compact rows (xg), silu -> bf16
// V=3: MoE2 compact rows, gate-scaled store to slot buffer
// ---------------------------------------------------------------------------
template <int V, int RT>
__global__ __launch_bounds__(256) void mgemm(
    const short* __restrict__ A, const short* __restrict__ Bt,
    const float* __restrict__ bias, float* __restrict__ C,
    short* __restrict__ Cb, const float* __restrict__ res, int K, int M,
    const int* __restrict__ offs, const float* __restrict__ tok_gate)
{
    int e = (V >= 2) ? blockIdx.z : 0;
    const short* Bte = (V >= 2) ? Bt + (size_t)e * M * K : Bt;
    const float* be  = (V >= 2) ? bias + (size_t)e * M : bias;

    int row_lo, row_hi;
    if (V >= 2) {
        row_lo = offs[e] + blockIdx.y * RT;
        row_hi = offs[e + 1];
        if (row_lo >= row_hi) return;
    } else {
        row_lo = blockIdx.y * RT;
        row_hi = 1 << 30;
    }
    int col0 = blockIdx.x * 64;

    __shared__ short As[RT * 40];    // row stride 40 shorts (80B): fragment
    __shared__ short Bs[64 * 40];    // b128 reads land 2-way max = free

    int t = threadIdx.x;
    int arow, ak;
    if (RT == 128) { arow = t >> 1; ak = (t & 1) * 16; }
    else           { arow = t >> 2; ak = (t & 3) * 8;  }
    int brow = t >> 2, bk = (t & 3) * 8;

    int  agrow = row_lo + arow;
    bool aval  = (V < 2) || (agrow < row_hi);
    int  asrc  = aval ? agrow : row_lo;
    const short* aptr = A   + (size_t)asrc * K + ak;
    const short* bptr = Bte + (size_t)(col0 + brow) * K + bk;
    short* as_dst = &As[arow * 40 + ak];
    short* bs_dst = &Bs[brow * 40 + bk];

    int lane = t & 63, wave = t >> 6;
    constexpr int AI = RT / 32;           // 4 (RT=128) or 2 (RT=64)
    int wm = (wave & 1) * (RT / 2), wn = (wave >> 1) * 32;
    int rin = lane & 15, quad = lane >> 4;

    floatx4 acc[AI][2];
    #pragma unroll
    for (int i = 0; i < AI; ++i)
        #pragma unroll
        for (int j = 0; j < 2; ++j)
            acc[i][j] = (floatx4){0.f, 0.f, 0.f, 0.f};

    // --- software pipeline: preload tile 0 ---
    float4 a0, a1, b0;
    a0 = *(const float4*)(aptr);
    if (RT == 128) a1 = *(const float4*)(aptr + 8);
    b0 = *(const float4*)(bptr);

    for (int k0 = 0; k0 < K; k0 += 32) {
        __syncthreads();   // WAR vs previous iteration's fragment reads
        *(float4*)(as_dst) = a0;
        if (RT == 128) *(float4*)(as_dst + 8) = a1;
        *(float4*)(bs_dst) = b0;
        __syncthreads();
        if (k0 + 32 < K) {   // issue next tile's loads; in flight during MFMA
            a0 = *(const float4*)(aptr + k0 + 32);
            if (RT == 128) a1 = *(const float4*)(aptr + k0 + 40);
            b0 = *(const float4*)(bptr + k0 + 32);
        }
        bf16x8 af[AI], bfr[2];
        #pragma unroll
        for (int i = 0; i < AI; ++i)
            af[i] = *(const bf16x8*)&As[(wm + i * 16 + rin) * 40 + quad * 8];
        #pragma unroll
        for (int j = 0; j < 2; ++j)
            bfr[j] = *(const bf16x8*)&Bs[(wn + j * 16 + rin) * 40 + quad * 8];
        #pragma unroll
        for (int i = 0; i < AI; ++i)
            #pragma unroll
            for (int j = 0; j < 2; ++j)
                acc[i][j] = __builtin_amdgcn_mfma_f32_16x16x32_bf16(
                    af[i], bfr[j], acc[i][j], 0, 0, 0);
    }

    // Epilogue. C/D layout: col = lane&15, row = quad*4 + reg  [m89-verified]
    #pragma unroll
    for (int i = 0; i < AI; ++i) {
        #pragma unroll
        for (int j = 0; j < 2; ++j) {
            int cg = col0 + wn + j * 16 + rin;
            #pragma unroll
            for (int rr = 0; rr < 4; ++rr) {
                int rg = row_lo + wm + i * 16 + quad * 4 + rr;
                float val = acc[i][j][rr];
                if (V == 0) {
                    C[(size_t)rg * M + cg] = val + be[cg];
                } else if (V == 1) {
                    C[(size_t)rg * M + cg] = val + be[cg] + res[(size_t)rg * M + cg];
                } else if (V == 2) {
                    if (rg < row_hi) {
                        float vb_ = val + be[cg];
                        Cb[(size_t)rg * M + cg] = f2bf(vb_ / (1.f + __expf(-vb_)));
                    }
                } else {
                    if (rg < row_hi)
                        C[(size_t)rg * M + cg] = tok_gate[rg] * (val + be[cg]);
                }
            }
        }
    }
}

// ---------------------------------------------------------------------------
// Sliding-window attention — fp32 math, conflict-free LDS (R5-proven)
// ---------------------------------------------------------------------------
__global__ __launch_bounds__(256) void attn_kernel(
    const float* __restrict__ qkv, const float* __restrict__ sink_ptr,
    short* __restrict__ ao)
{
    __shared__ __align__(16) float KT[32 * KPITCH * 4];
    __shared__ __align__(16) float Vs[WROWS * VPADF];
    __shared__ __align__(16) float Ps4[4][64][4];

    int qblk = blockIdx.x;          // 0..S/QB-1
    int kvh  = blockIdx.y;          // 0..NKV-1
    int q0   = qblk * QB;
    int jbase = q0 - (WS_ - 1);

    int t = threadIdx.x;
    int c4 = (t & 31) * 4, c4g = t & 31;
    for (int r = t >> 5; r < WROWS; r += 8) {
        int j = jbase + r;
        float4 kv4 = make_float4(0.f, 0.f, 0.f, 0.f);
        float4 vv4 = make_float4(0.f, 0.f, 0.f, 0.f);
        if (j >= 0) {
            kv4 = *(const float4*)(qkv + (size_t)j * QKV_M + KOFF + kvh * HD + c4);
            vv4 = *(const float4*)(qkv + (size_t)j * QKV_M + VOFF + kvh * HD + c4);
        }
        *(float4*)&KT[(c4g * KPITCH + r) * 4] = kv4;
        *(float4*)&Vs[r * VPADF + c4] = vv4;
    }
    __syncthreads();

    int lane = t & 63, wv = t >> 6;
    float sink = sink_ptr[0];
    const float rscale = 0.08838834764831845f;  // 1/sqrt(128)

    #pragma unroll
    for (int g = 0; g < 2; ++g) {
        int qi = wv * 2 + g;
        int i  = q0 + qi;
        bool valid = (jbase + qi + lane) >= 0;

        float sc[4] = {0.f, 0.f, 0.f, 0.f};
        const float* qbase = qkv + (size_t)i * QKV_M + (kvh * 4) * HD;
        #pragma unroll
        for (int c = 0; c < 32; ++c) {
            float4 kx = *(const float4*)&KT[(c * KPITCH + qi + lane) * 4];
            #pragma unroll
            for (int hh = 0; hh < 4; ++hh) {
                float4 q4 = *(const float4*)(qbase + hh * HD + c * 4);
                sc[hh] += q4.x*kx.x + q4.y*kx.y + q4.z*kx.z + q4.w*kx.w;
            }
        }

        float pn[4];
        #pragma unroll
        for (int hh = 0; hh < 4; ++hh) {
            float s = valid ? sc[hh] * rscale : -1e30f;
            float m = s;
            #pragma unroll
            for (int off = 32; off; off >>= 1) m = fmaxf(m, __shfl_xor(m, off, 64));
            float mf = fmaxf(m, sink);
            float p  = __expf(s - mf);
            float ds = p;
            #pragma unroll
            for (int off = 32; off; off >>= 1) ds += __shfl_xor(ds, off, 64);
            pn[hh] = p / (ds + __expf(sink - mf));
        }
        *(float4*)&Ps4[wv][lane][0] = make_float4(pn[0], pn[1], pn[2], pn[3]);

        float o0=0,o1=0,o2=0,o3=0,o4=0,o5=0,o6=0,o7=0;
        const float* vp = &Vs[qi * VPADF + 2 * lane];
        #pragma unroll
        for (int jj = 0; jj < 64; ++jj) {
            float4 p4 = *(const float4*)&Ps4[wv][jj][0];   // uniform broadcast
            float2 vv = *(const float2*)(vp + jj * VPADF);
            o0 += p4.x * vv.x; o1 += p4.x * vv.y;
            o2 += p4.y * vv.x; o3 += p4.y * vv.y;
            o4 += p4.z * vv.x; o5 += p4.z * vv.y;
            o6 += p4.w * vv.x; o7 += p4.w * vv.y;
        }
        short2 r0; r0.x = f2bf(o0); r0.y = f2bf(o1);
        short2 r1; r1.x = f2bf(o2); r1.y = f2bf(o3);
        short2 r2; r2.x = f2bf(o4); r2.y = f2bf(o5);
        short2 r3; r3.x = f2bf(o6); r3.y = f2bf(o7);
        ((short2*)(ao + (size_t)i * D + (kvh * 4 + 0) * HD))[lane] = r0;
        ((short2*)(ao + (size_t)i * D + (kvh * 4 + 1) * HD))[lane] = r1;
        ((short2*)(ao + (size_t)i * D + (kvh * 4 + 2) * HD))[lane] = r2;
        ((short2*)(ao + (size_t)i * D + (kvh * 4 + 3) * HD))[lane] = r3;
    }
}

// ---------------------------------------------------------------------------
// Fused RMSNorm2 + router
// ---------------------------------------------------------------------------
__global__ __launch_bounds__(256) void rms_router_kernel(
    const float* __restrict__ x1, const float* __restrict__ w,
    short* __restrict__ h2b,
    const float* __restrict__ rw, const float* __restrict__ rb,
    int* __restrict__ cnt, float* __restrict__ colsum,
    int* __restrict__ top_i, float* __restrict__ top_g)
{
    int tok = blockIdx.x, t = threadIdx.x;
    __shared__ float hrow[D];
    float4 v = ((const float4*)(x1 + (size_t)tok * D))[t];
    float ss = v.x*v.x + v.y*v.y + v.z*v.z + v.w*v.w;
    #pragma unroll
    for (int off = 32; off; off >>= 1) ss += __shfl_xor(ss, off, 64);
    __shared__ float red[4];
    if ((t & 63) == 0) red[t >> 6] = ss;
    __syncthreads();
    float total = red[0] + red[1] + red[2] + red[3];
    float scale = rsqrtf(total * (1.0f / (float)D) + 1e-6f);
    float4 wv = ((const float4*)w)[t];
    float4 o;
    o.x = v.x * scale * wv.x; o.y = v.y * scale * wv.y;
    o.z = v.z * scale * wv.z; o.w = v.w * scale * wv.w;
    ((float4*)hrow)[t] = o;
    short4 ob;
    ob.x = f2bf(o.x); ob.y = f2bf(o.y); ob.z = f2bf(o.z); ob.w = f2bf(o.w);
    ((short4*)(h2b + (size_t)tok * D))[t] = ob;
    __syncthreads();

    int e = t & 15, seg = t >> 4;
    float part = 0.f;
    int d0 = seg * 64;
    for (int d = d0; d < d0 + 64; ++d) part += hrow[d] * rw[d * E_ + e];
    __shared__ float lpart[256];
    lpart[t] = part;
    __syncthreads();
    __shared__ float logits[E_];
    if (t < E_) {
        float sl = 0.f;
        for (int sg = 0; sg < 16; ++sg) sl += lpart[sg * 16 + t];
        logits[t] = (sl + rb[t]) * 10.0f;   // /0.1
    }
    __syncthreads();
    __shared__ float sm[2];
    if (t == 0) {
        float mx = logits[0];
        for (int x = 1; x < E_; ++x) mx = fmaxf(mx, logits[x]);
        float ps = 0.f;
        for (int x = 0; x < E_; ++x) ps += __expf(logits[x] - mx);
        sm[0] = mx; sm[1] = ps;
        int i0 = 0; float v0 = logits[0];
        for (int x = 1; x < E_; ++x) if (logits[x] > v0) { v0 = logits[x]; i0 = x; }
        int i1 = -1; float v1 = -3.4e38f;
        for (int x = 0; x < E_; ++x) {
            if (x == i0) continue;
            if (logits[x] > v1) { v1 = logits[x]; i1 = x; }
        }
        float e1 = __expf(v1 - v0);
        float g0 = 1.f / (1.f + e1);
        float g1 = e1 * g0;
        top_i[tok * 2 + 0] = i0; top_g[tok * 2 + 0] = g0;
        top_i[tok * 2 + 1] = i1; top_g[tok * 2 + 1] = g1;
        atomicAdd(&cnt[i0], 1);
        atomicAdd(&cnt[i1], 1);
    }
    __syncthreads();
    if (t < E_) atomicAdd(&colsum[t], __expf(logits[t] - sm[0]) / sm[1]);
}

__global__ void offsets_kernel(const int* __restrict__ cnt, int* __restrict__ offs,
                               int* __restrict__ cursor,
                               const float* __restrict__ colsum,
                               float* __restrict__ aux_out)
{
    if (threadIdx.x == 0) {
        int acc = 0;
        for (int e = 0; e < E_; ++e) { offs[e] = acc; cursor[e] = acc; acc += cnt[e]; }
        offs[E_] = acc;
        float s = 0.f;
        for (int e = 0; e < E_; ++e) s += colsum[e] * colsum[e];
        *aux_out = s / (float)E_ * 1e-5f;
    }
}

__global__ __launch_bounds__(256) void scatter_kernel(
    const int* __restrict__ top_i, const float* __restrict__ top_g,
    int* __restrict__ cursor, int* __restrict__ tok_idx,
    float* __restrict__ tok_gate, int* __restrict__ slot_of)
{
    int tok = blockIdx.x * 256 + threadIdx.x;
    if (tok >= NTOK) return;
    for (int s = 0; s < TOPK; ++s) {
        int e = top_i[tok * 2 + s];
        int pos = atomicAdd(&cursor[e], 1);
        tok_idx[pos]  = tok;
        tok_gate[pos] = top_g[tok * 2 + s];
        slot_of[tok * 2 + s] = pos;
    }
}

// xg[slot] = h2b[tok_idx[slot]]  (coalesced row copy, 2 slots per block)
__global__ __launch_bounds__(256) void gather_kernel(
    const short* __restrict__ h2b, const int* __restrict__ tok_idx,
    short* __restrict__ xg)
{
    int slot = blockIdx.x * 2 + (threadIdx.x >> 7);
    int c = (threadIdx.x & 127) * 8;
    int tok = tok_idx[slot];
    *(float4*)&xg[(size_t)slot * D + c] =
        *(const float4*)&h2b[(size_t)tok * D + c];
}

// out[tok] = x1[tok] + y[slot0] + y[slot1]
__global__ __launch_bounds__(256) void combine_kernel(
    const float* __restrict__ x1, const float* __restrict__ y,
    const int* __restrict__ slot_of, float* __restrict__ out)
{
    int tok = blockIdx.x, t = threadIdx.x;
    int s0 = slot_of[tok * 2], s1 = slot_of[tok * 2 + 1];
    float4 a = ((const float4*)(x1 + (size_t)tok * D))[t];
    float4 b = ((const float4*)(y + (size_t)s0 * D))[t];
    float4 c = ((const float4*)(y + (size_t)s1 * D))[t];
    float4 o;
    o.x = a.x + b.x + c.x; o.y = a.y + b.y + c.y;
    o.z = a.z + b.z + c.z; o.w = a.w + b.w + c.w;
    ((float4*)(out + (size_t)tok * D))[t] = o;
}

// ---------------------------------------------------------------------------
extern "C" void kernel_launch(void* const* d_in, const int* in_sizes, int n_in,
                              void* d_out, int out_size, void* d_ws, size_t ws_size,
                              hipStream_t stream)
{
    const float* x        = (const float*)d_in[0];
    const float* norm1_w  = (const float*)d_in[1];
    const float* wq       = (const float*)d_in[2];
    const float* bq       = (const float*)d_in[3];
    const float* wk       = (const float*)d_in[4];
    const float* bk       = (const float*)d_in[5];
    const float* wv       = (const float*)d_in[6];
    const float* bv       = (const float*)d_in[7];
    const float* wo       = (const float*)d_in[8];
    const float* bo       = (const float*)d_in[9];
    const float* sink     = (const float*)d_in[10];
    const float* norm2_w  = (const float*)d_in[11];
    const float* router_w = (const float*)d_in[12];
    const float* router_b = (const float*)d_in[13];
    const float* w1       = (const float*)d_in[14];
    const float* b1       = (const float*)d_in[15];
    const float* w2       = (const float*)d_in[16];
    const float* b2       = (const float*)d_in[17];
    float* out = (float*)d_out;

    // workspace layout
    char* w = (char*)d_ws;
    auto alloc = [&](size_t bytes) {
        char* p = w; w += (bytes + 255) & ~255ull; return p;
    };
    short* wqkvT = (short*)alloc((size_t)QKV_M * D * 2);       // [1536][1024]
    short* woT   = (short*)alloc((size_t)D * D * 2);           // [1024][1024]
    short* w1T   = (short*)alloc((size_t)E_ * HDIM * D * 2);   // [16][512][1024]
    short* w2T   = (short*)alloc((size_t)E_ * D * HDIM * 2);   // [16][1024][512]
    float* bqkv  = (float*)alloc(QKV_M * 4);
    short* h_bf  = (short*)alloc((size_t)S * D * 2);
    float* qkv   = (float*)alloc((size_t)S * QKV_M * 4);
    float* x1    = (float*)alloc((size_t)S * D * 4);
    short* h2b   = (short*)alloc((size_t)S * D * 2);
    short* xg    = (short*)alloc((size_t)NSLOT * D * 2);       // 8.4 MB
    float* yslot = (float*)alloc((size_t)NSLOT * D * 4);       // 16.8 MB
    int*   cnt      = (int*)alloc(32 * 4);   // cnt[16] + colsum[16]
    float* colsum   = (float*)(cnt + 16);
    int*   offs     = (int*)alloc(17 * 4);
    int*   cursor   = (int*)alloc(16 * 4);
    int*   top_i    = (int*)alloc((size_t)NSLOT * 4);
    float* top_g    = (float*)alloc((size_t)NSLOT * 4);
    int*   tok_idx  = (int*)alloc((size_t)NSLOT * 4);
    float* tok_gate = (float*)alloc((size_t)NSLOT * 4);
    int*   slot_of  = (int*)alloc((size_t)NSLOT * 4);
    // aliases (lifetimes don't overlap):
    short* ao_bf = h_bf;          // h_bf dead after QKV GEMM
    short* hmid  = (short*)qkv;   // qkv dead after attention

    hipMemsetAsync(cnt, 0, 32 * 4, stream);

    // 0) all weight prep in one launch
    tconv_all<<<18950, 256, 0, stream>>>(wq, wk, wv, wo, w1, w2, bq, bk, bv,
                                         wqkvT, woT, w1T, w2T, bqkv);

    // 1) h = rmsnorm(x) -> bf16
    rmsnorm_kernel<<<S, 256, 0, stream>>>(x, norm1_w, h_bf);

    // 2) fused QKV: qkv = h @ [wq|wk|wv] + [bq|bk|bv]   (384 blocks)
    mgemm<0, 128><<<dim3(QKV_M / 64, S / 128), 256, 0, stream>>>(
        h_bf, wqkvT, bqkv, qkv, nullptr, nullptr, D, QKV_M, nullptr, nullptr);

    // 3) attention -> bf16 ao   (512 blocks)
    attn_kernel<<<dim3(S / QB, NKV), 256, 0, stream>>>(qkv, sink, ao_bf);

    // 4) x1 = x + ao@wo + bo   (256 blocks)
    mgemm<1, 128><<<dim3(D / 64, S / 128), 256, 0, stream>>>(
        ao_bf, woT, bo, x1, nullptr, x, D, D, nullptr, nullptr);

    // 5+6) fused rmsnorm2 + router
    rms_router_kernel<<<NTOK, 256, 0, stream>>>(x1, norm2_w, h2b,
                                                router_w, router_b,
                                                cnt, colsum, top_i, top_g);

    // 7) offsets + aux loss -> out[S*D]
    offsets_kernel<<<1, 64, 0, stream>>>(cnt, offs, cursor, colsum,
                                         out + (size_t)S * D);

    // 8) scatter token slots expert-contiguously (+ inverse slot map)
    scatter_kernel<<<(NTOK + 255) / 256, 256, 0, stream>>>(
        top_i, top_g, cursor, tok_idx, tok_gate, slot_of);

    // 8b) pre-gather activations into slot order (coalesced; kills the
    //     per-K-iter random row gather that made MoE1 latency-bound)
    gather_kernel<<<NSLOT / 2, 256, 0, stream>>>(h2b, tok_idx, xg);

    // 9) MoE GEMM1: hmid[slot] = silu(xg[slot] @ w1[e] + b1[e]) -> bf16
    mgemm<2, 64><<<dim3(HDIM / 64, 32, E_), 256, 0, stream>>>(
        xg, w1T, b1, nullptr, hmid, nullptr, D, HDIM, offs, nullptr);

    // 10) MoE GEMM2: yslot[slot] = gate * (hmid @ w2[e] + b2[e])
    mgemm<3, 64><<<dim3(D / 64, 32, E_), 256, 0, stream>>>(
        hmid, w2T, b2, yslot, nullptr, nullptr, HDIM, D, offs, tok_gate);

    // 11) out = x1 + yslot[slot0] + yslot[slot1]
    combine_kernel<<<NTOK, 256, 0, stream>>>(x1, yslot, slot_of, out);
}

// Round 7
// 329.807 us; speedup vs baseline: 2.6801x; 1.0879x over previous
//
#include <hip/hip_runtime.h>
#include <hip/hip_bf16.h>

// Problem constants
#define S     2048
#define D     1024
#define NH    8
#define NKV   2
#define HD    128
#define WS_   64
#define E_    16
#define HDIM  512
#define TOPK  2
#define NTOK  S
#define NSLOT (S*TOPK)         // 4096
#define QKV_M (D + 2*NKV*HD)   // 1536 fused q|k|v columns
#define KOFF  D                // 1024
#define VOFF  (D + NKV*HD)     // 1280
#define QB    8                // queries per attention block
#define WROWS (QB + WS_ - 1)   // 71 key rows per window
#define KPITCH 73              // KT key pitch (float4 units)
#define VPADF  132             // Vs row stride in floats

typedef __attribute__((ext_vector_type(8))) short bf16x8;
typedef __attribute__((ext_vector_type(4))) float floatx4;

__device__ inline short f2bf(float f) {
    __hip_bfloat16 b = __float2bfloat16(f);
    return *reinterpret_cast<short*>(&b);
}

// ---------------------------------------------------------------------------
// All weight prep in ONE launch: 6 transpose+convert regions + bias concat
// + fp32 router_w transpose (rwT[16][1024]).
// ---------------------------------------------------------------------------
__global__ __launch_bounds__(256) void tconv_all(
    const float* __restrict__ wq, const float* __restrict__ wk,
    const float* __restrict__ wv, const float* __restrict__ wo,
    const float* __restrict__ w1, const float* __restrict__ w2,
    const float* __restrict__ bq, const float* __restrict__ bk,
    const float* __restrict__ bv, const float* __restrict__ router_w,
    short* __restrict__ wqkvT, short* __restrict__ woT,
    short* __restrict__ w1T, short* __restrict__ w2T,
    float* __restrict__ bqkv, float* __restrict__ rwT)
{
    int id = blockIdx.x;
    if (id >= 18950) {                       // 32 router_w transpose blocks
        int ky = id - 18950;                 // 0..31
        int t = threadIdx.x;
        int r = t >> 4, c = t & 15;
        int k0 = ky * 32;
        rwT[c * D + k0 + r]      = router_w[(k0 + r) * E_ + c];
        rwT[c * D + k0 + r + 16] = router_w[(k0 + r + 16) * E_ + c];
        return;
    }
    if (id >= 18944) {                       // 6 bias-concat blocks
        int t = (id - 18944) * 256 + threadIdx.x;
        if (t < D) bqkv[t] = bq[t];
        else if (t < VOFF) bqkv[t] = bk[t - D];
        else bqkv[t] = bv[t - VOFF];
        return;
    }
    const float* in; short* outp; int K, M, mx, ky;
    if (id < 1024)      { in = wq; outp = wqkvT;                  K = D; M = D;   int l = id;        mx = l & 31; ky = l >> 5; }
    else if (id < 1280) { in = wk; outp = wqkvT + (size_t)KOFF*D; K = D; M = 256; int l = id - 1024; mx = l & 7;  ky = l >> 3; }
    else if (id < 1536) { in = wv; outp = wqkvT + (size_t)VOFF*D; K = D; M = 256; int l = id - 1280; mx = l & 7;  ky = l >> 3; }
    else if (id < 2560) { in = wo; outp = woT;                    K = D; M = D;   int l = id - 1536; mx = l & 31; ky = l >> 5; }
    else if (id < 10752){ int l = id - 2560;  int e = l >> 9; int r = l & 511;
                          in = w1 + (size_t)e * D * HDIM; outp = w1T + (size_t)e * D * HDIM;
                          K = D; M = HDIM; mx = r & 15; ky = r >> 4; }
    else                { int l = id - 10752; int e = l >> 9; int r = l & 511;
                          in = w2 + (size_t)e * D * HDIM; outp = w2T + (size_t)e * D * HDIM;
                          K = HDIM; M = D; mx = r & 31; ky = r >> 5; }
    __shared__ float tile[32][33];
    int t = threadIdx.x, r = t >> 3, c4 = (t & 7) * 4;
    int k0 = ky * 32, m0 = mx * 32;
    float4 v = *(const float4*)&in[(size_t)(k0 + r) * M + m0 + c4];
    tile[r][c4 + 0] = v.x; tile[r][c4 + 1] = v.y;
    tile[r][c4 + 2] = v.z; tile[r][c4 + 3] = v.w;
    __syncthreads();
    short4 o;
    o.x = f2bf(tile[c4 + 0][r]);
    o.y = f2bf(tile[c4 + 1][r]);
    o.z = f2bf(tile[c4 + 2][r]);
    o.w = f2bf(tile[c4 + 3][r]);
    *(short4*)&outp[(size_t)(m0 + r) * K + k0 + c4] = o;
}

// ---------------------------------------------------------------------------
// RMSNorm (attention pre-norm): fp32 in -> bf16 out
// ---------------------------------------------------------------------------
__global__ __launch_bounds__(256) void rmsnorm_kernel(
    const float* __restrict__ x, const float* __restrict__ w,
    short* __restrict__ outb)
{
    int row = blockIdx.x, t = threadIdx.x;
    float4 v = ((const float4*)(x + (size_t)row * D))[t];
    float ss = v.x*v.x + v.y*v.y + v.z*v.z + v.w*v.w;
    #pragma unroll
    for (int off = 32; off; off >>= 1) ss += __shfl_xor(ss, off, 64);
    __shared__ float red[4];
    if ((t & 63) == 0) red[t >> 6] = ss;
    __syncthreads();
    float total = red[0] + red[1] + red[2] + red[3];
    float scale = rsqrtf(total * (1.0f / (float)D) + 1e-6f);
    float4 wv = ((const float4*)w)[t];
    short4 ob;
    ob.x = f2bf(v.x * scale * wv.x); ob.y = f2bf(v.y * scale * wv.y);
    ob.z = f2bf(v.z * scale * wv.z); ob.w = f2bf(v.w * scale * wv.w);
    ((short4*)(outb + (size_t)row * D))[t] = ob;
}

// ---------------------------------------------------------------------------
// bf16 MFMA GEMM: C[N,M] = A[N,K](bf16) @ Bt[M,K]^T(bf16) + bias
// RT x 64 block tile, BK=32, 4 waves (2x2), software-pipelined K-loop.
// V=0: C fp32 (fused QKV)   V=1: C = acc+bias+res (WO + residual -> x1)
// V=2: MoE1 compact rows (xg), silu -> bf16
// V=3: MoE2 compact rows, gate-scaled store to slot buffer
// ---------------------------------------------------------------------------
template <int V, int RT>
__global__ __launch_bounds__(256) void mgemm(
    const short* __restrict__ A, const short* __restrict__ Bt,
    const float* __restrict__ bias, float* __restrict__ C,
    short* __restrict__ Cb, const float* __restrict__ res, int K, int M,
    const int* __restrict__ offs, const float* __restrict__ tok_gate)
{
    int e = (V >= 2) ? blockIdx.z : 0;
    const short* Bte = (V >= 2) ? Bt + (size_t)e * M * K : Bt;
    const float* be  = (V >= 2) ? bias + (size_t)e * M : bias;

    int row_lo, row_hi;
    if (V >= 2) {
        row_lo = offs[e] + blockIdx.y * RT;
        row_hi = offs[e + 1];
        if (row_lo >= row_hi) return;
    } else {
        row_lo = blockIdx.y * RT;
        row_hi = 1 << 30;
    }
    int col0 = blockIdx.x * 64;

    __shared__ short As[RT * 40];
    __shared__ short Bs[64 * 40];

    int t = threadIdx.x;
    int arow, ak;
    if (RT == 128) { arow = t >> 1; ak = (t & 1) * 16; }
    else           { arow = t >> 2; ak = (t & 3) * 8;  }
    int brow = t >> 2, bk = (t & 3) * 8;

    int  agrow = row_lo + arow;
    bool aval  = (V < 2) || (agrow < row_hi);
    int  asrc  = aval ? agrow : row_lo;
    const short* aptr = A   + (size_t)asrc * K + ak;
    const short* bptr = Bte + (size_t)(col0 + brow) * K + bk;
    short* as_dst = &As[arow * 40 + ak];
    short* bs_dst = &Bs[brow * 40 + bk];

    int lane = t & 63, wave = t >> 6;
    constexpr int AI = RT / 32;
    int wm = (wave & 1) * (RT / 2), wn = (wave >> 1) * 32;
    int rin = lane & 15, quad = lane >> 4;

    floatx4 acc[AI][2];
    #pragma unroll
    for (int i = 0; i < AI; ++i)
        #pragma unroll
        for (int j = 0; j < 2; ++j)
            acc[i][j] = (floatx4){0.f, 0.f, 0.f, 0.f};

    float4 a0, a1, b0;
    a0 = *(const float4*)(aptr);
    if (RT == 128) a1 = *(const float4*)(aptr + 8);
    b0 = *(const float4*)(bptr);

    for (int k0 = 0; k0 < K; k0 += 32) {
        __syncthreads();
        *(float4*)(as_dst) = a0;
        if (RT == 128) *(float4*)(as_dst + 8) = a1;
        *(float4*)(bs_dst) = b0;
        __syncthreads();
        if (k0 + 32 < K) {
            a0 = *(const float4*)(aptr + k0 + 32);
            if (RT == 128) a1 = *(const float4*)(aptr + k0 + 40);
            b0 = *(const float4*)(bptr + k0 + 32);
        }
        bf16x8 af[AI], bfr[2];
        #pragma unroll
        for (int i = 0; i < AI; ++i)
            af[i] = *(const bf16x8*)&As[(wm + i * 16 + rin) * 40 + quad * 8];
        #pragma unroll
        for (int j = 0; j < 2; ++j)
            bfr[j] = *(const bf16x8*)&Bs[(wn + j * 16 + rin) * 40 + quad * 8];
        #pragma unroll
        for (int i = 0; i < AI; ++i)
            #pragma unroll
            for (int j = 0; j < 2; ++j)
                acc[i][j] = __builtin_amdgcn_mfma_f32_16x16x32_bf16(
                    af[i], bfr[j], acc[i][j], 0, 0, 0);
    }

    #pragma unroll
    for (int i = 0; i < AI; ++i) {
        #pragma unroll
        for (int j = 0; j < 2; ++j) {
            int cg = col0 + wn + j * 16 + rin;
            #pragma unroll
            for (int rr = 0; rr < 4; ++rr) {
                int rg = row_lo + wm + i * 16 + quad * 4 + rr;
                float val = acc[i][j][rr];
                if (V == 0) {
                    C[(size_t)rg * M + cg] = val + be[cg];
                } else if (V == 1) {
                    C[(size_t)rg * M + cg] = val + be[cg] + res[(size_t)rg * M + cg];
                } else if (V == 2) {
                    if (rg < row_hi) {
                        float vb_ = val + be[cg];
                        Cb[(size_t)rg * M + cg] = f2bf(vb_ / (1.f + __expf(-vb_)));
                    }
                } else {
                    if (rg < row_hi)
                        C[(size_t)rg * M + cg] = tok_gate[rg] * (val + be[cg]);
                }
            }
        }
    }
}

// ---------------------------------------------------------------------------
// Sliding-window attention — fp32 math, conflict-free LDS (R5-proven)
// ---------------------------------------------------------------------------
__global__ __launch_bounds__(256) void attn_kernel(
    const float* __restrict__ qkv, const float* __restrict__ sink_ptr,
    short* __restrict__ ao)
{
    __shared__ __align__(16) float KT[32 * KPITCH * 4];
    __shared__ __align__(16) float Vs[WROWS * VPADF];
    __shared__ __align__(16) float Ps4[4][64][4];

    int qblk = blockIdx.x;
    int kvh  = blockIdx.y;
    int q0   = qblk * QB;
    int jbase = q0 - (WS_ - 1);

    int t = threadIdx.x;
    int c4 = (t & 31) * 4, c4g = t & 31;
    for (int r = t >> 5; r < WROWS; r += 8) {
        int j = jbase + r;
        float4 kv4 = make_float4(0.f, 0.f, 0.f, 0.f);
        float4 vv4 = make_float4(0.f, 0.f, 0.f, 0.f);
        if (j >= 0) {
            kv4 = *(const float4*)(qkv + (size_t)j * QKV_M + KOFF + kvh * HD + c4);
            vv4 = *(const float4*)(qkv + (size_t)j * QKV_M + VOFF + kvh * HD + c4);
        }
        *(float4*)&KT[(c4g * KPITCH + r) * 4] = kv4;
        *(float4*)&Vs[r * VPADF + c4] = vv4;
    }
    __syncthreads();

    int lane = t & 63, wv = t >> 6;
    float sink = sink_ptr[0];
    const float rscale = 0.08838834764831845f;

    #pragma unroll
    for (int g = 0; g < 2; ++g) {
        int qi = wv * 2 + g;
        int i  = q0 + qi;
        bool valid = (jbase + qi + lane) >= 0;

        float sc[4] = {0.f, 0.f, 0.f, 0.f};
        const float* qbase = qkv + (size_t)i * QKV_M + (kvh * 4) * HD;
        #pragma unroll
        for (int c = 0; c < 32; ++c) {
            float4 kx = *(const float4*)&KT[(c * KPITCH + qi + lane) * 4];
            #pragma unroll
            for (int hh = 0; hh < 4; ++hh) {
                float4 q4 = *(const float4*)(qbase + hh * HD + c * 4);
                sc[hh] += q4.x*kx.x + q4.y*kx.y + q4.z*kx.z + q4.w*kx.w;
            }
        }

        float pn[4];
        #pragma unroll
        for (int hh = 0; hh < 4; ++hh) {
            float s = valid ? sc[hh] * rscale : -1e30f;
            float m = s;
            #pragma unroll
            for (int off = 32; off; off >>= 1) m = fmaxf(m, __shfl_xor(m, off, 64));
            float mf = fmaxf(m, sink);
            float p  = __expf(s - mf);
            float ds = p;
            #pragma unroll
            for (int off = 32; off; off >>= 1) ds += __shfl_xor(ds, off, 64);
            pn[hh] = p / (ds + __expf(sink - mf));
        }
        *(float4*)&Ps4[wv][lane][0] = make_float4(pn[0], pn[1], pn[2], pn[3]);

        float o0=0,o1=0,o2=0,o3=0,o4=0,o5=0,o6=0,o7=0;
        const float* vp = &Vs[qi * VPADF + 2 * lane];
        #pragma unroll
        for (int jj = 0; jj < 64; ++jj) {
            float4 p4 = *(const float4*)&Ps4[wv][jj][0];
            float2 vv = *(const float2*)(vp + jj * VPADF);
            o0 += p4.x * vv.x; o1 += p4.x * vv.y;
            o2 += p4.y * vv.x; o3 += p4.y * vv.y;
            o4 += p4.z * vv.x; o5 += p4.z * vv.y;
            o6 += p4.w * vv.x; o7 += p4.w * vv.y;
        }
        short2 r0; r0.x = f2bf(o0); r0.y = f2bf(o1);
        short2 r1; r1.x = f2bf(o2); r1.y = f2bf(o3);
        short2 r2; r2.x = f2bf(o4); r2.y = f2bf(o5);
        short2 r3; r3.x = f2bf(o6); r3.y = f2bf(o7);
        ((short2*)(ao + (size_t)i * D + (kvh * 4 + 0) * HD))[lane] = r0;
        ((short2*)(ao + (size_t)i * D + (kvh * 4 + 1) * HD))[lane] = r1;
        ((short2*)(ao + (size_t)i * D + (kvh * 4 + 2) * HD))[lane] = r2;
        ((short2*)(ao + (size_t)i * D + (kvh * 4 + 3) * HD))[lane] = r3;
    }
}

// ---------------------------------------------------------------------------
// Fused RMSNorm2 + router. No atomics: writes probs[tok][16] + top_i/top_g.
// Logits dot uses fp32 rwT[16][1024] -> 16 independent float4 loads/lane.
// Summation element order identical to the R6-passing kernel.
// ---------------------------------------------------------------------------
__global__ __launch_bounds__(256) void rms_router_kernel(
    const float* __restrict__ x1, const float* __restrict__ w,
    short* __restrict__ h2b, const float* __restrict__ rwT,
    const float* __restrict__ rb, float* __restrict__ probs,
    int* __restrict__ top_i, float* __restrict__ top_g)
{
    int tok = blockIdx.x, t = threadIdx.x;
    __shared__ float hrow[D];
    float4 v = ((const float4*)(x1 + (size_t)tok * D))[t];
    float ss = v.x*v.x + v.y*v.y + v.z*v.z + v.w*v.w;
    #pragma unroll
    for (int off = 32; off; off >>= 1) ss += __shfl_xor(ss, off, 64);
    __shared__ float red[4];
    if ((t & 63) == 0) red[t >> 6] = ss;
    __syncthreads();
    float total = red[0] + red[1] + red[2] + red[3];
    float scale = rsqrtf(total * (1.0f / (float)D) + 1e-6f);
    float4 wv = ((const float4*)w)[t];
    float4 o;
    o.x = v.x * scale * wv.x; o.y = v.y * scale * wv.y;
    o.z = v.z * scale * wv.z; o.w = v.w * scale * wv.w;
    ((float4*)hrow)[t] = o;
    short4 ob;
    ob.x = f2bf(o.x); ob.y = f2bf(o.y); ob.z = f2bf(o.z); ob.w = f2bf(o.w);
    ((short4*)(h2b + (size_t)tok * D))[t] = ob;
    __syncthreads();

    // logits: thread (e = t&15, seg = t>>4) sums its 64-element K-slice,
    // vectorized float4; element order matches the scalar R6 loop.
    int e = t & 15, seg = t >> 4;
    const float4* rwp = (const float4*)(rwT + (size_t)e * D + seg * 64);
    const float4* hp  = (const float4*)(hrow + seg * 64);
    float part = 0.f;
    #pragma unroll
    for (int i = 0; i < 16; ++i) {
        float4 a = hp[i];
        float4 b = rwp[i];
        part += a.x * b.x; part += a.y * b.y;
        part += a.z * b.z; part += a.w * b.w;
    }
    __shared__ float lpart[256];
    lpart[t] = part;
    __syncthreads();
    __shared__ float logits[E_];
    if (t < E_) {
        float sl = 0.f;
        for (int sg = 0; sg < 16; ++sg) sl += lpart[sg * 16 + t];
        logits[t] = (sl + rb[t]) * 10.0f;   // /0.1
    }
    __syncthreads();
    __shared__ float sm[2];
    if (t == 0) {
        float mx = logits[0];
        for (int x = 1; x < E_; ++x) mx = fmaxf(mx, logits[x]);
        float ps = 0.f;
        for (int x = 0; x < E_; ++x) ps += __expf(logits[x] - mx);
        sm[0] = mx; sm[1] = ps;
        int i0 = 0; float v0 = logits[0];
        for (int x = 1; x < E_; ++x) if (logits[x] > v0) { v0 = logits[x]; i0 = x; }
        int i1 = -1; float v1 = -3.4e38f;
        for (int x = 0; x < E_; ++x) {
            if (x == i0) continue;
            if (logits[x] > v1) { v1 = logits[x]; i1 = x; }
        }
        float e1 = __expf(v1 - v0);
        float g0 = 1.f / (1.f + e1);
        float g1 = e1 * g0;
        top_i[tok * 2 + 0] = i0; top_g[tok * 2 + 0] = g0;
        top_i[tok * 2 + 1] = i1; top_g[tok * 2 + 1] = g1;
    }
    __syncthreads();
    if (t < E_) probs[tok * E_ + t] = __expf(logits[t] - sm[0]) / sm[1];
}

// ---------------------------------------------------------------------------
// Finalize: colsum + aux from probs; expert histogram from top_i; offs/cursor.
// One block, 256 threads, LDS-only reductions.
// ---------------------------------------------------------------------------
__global__ __launch_bounds__(256) void finalize_kernel(
    const float* __restrict__ probs, const int* __restrict__ top_i,
    int* __restrict__ offs, int* __restrict__ cursor,
    float* __restrict__ aux_out)
{
    __shared__ float csum[E_];
    __shared__ int hist[E_];
    int t = threadIdx.x;
    if (t < E_) { csum[t] = 0.f; hist[t] = 0; }
    __syncthreads();

    // colsum: fully-coalesced sweep of probs[2048][16]
    int c = t & 15, g = t >> 4;
    float part = 0.f;
    for (int i = 0; i < NTOK / 16; ++i)
        part += probs[(size_t)(i * 16 + g) * E_ + c];
    atomicAdd(&csum[c], part);

    // expert histogram from top_i[4096]
    int h = 0;  // (unused placeholder to keep structure clear)
    for (int i = 0; i < NSLOT / 256; ++i) {
        int eidx = top_i[i * 256 + t];
        atomicAdd(&hist[eidx], 1);
    }
    (void)h;
    __syncthreads();

    if (t == 0) {
        int acc = 0;
        for (int e = 0; e < E_; ++e) { offs[e] = acc; cursor[e] = acc; acc += hist[e]; }
        offs[E_] = acc;
        float s = 0.f;
        for (int e = 0; e < E_; ++e) s += csum[e] * csum[e];
        *aux_out = s / (float)E_ * 1e-5f;
    }
}

__global__ __launch_bounds__(256) void scatter_kernel(
    const int* __restrict__ top_i, const float* __restrict__ top_g,
    int* __restrict__ cursor, int* __restrict__ tok_idx,
    float* __restrict__ tok_gate, int* __restrict__ slot_of)
{
    int tok = blockIdx.x * 256 + threadIdx.x;
    if (tok >= NTOK) return;
    for (int s = 0; s < TOPK; ++s) {
        int e = top_i[tok * 2 + s];
        int pos = atomicAdd(&cursor[e], 1);
        tok_idx[pos]  = tok;
        tok_gate[pos] = top_g[tok * 2 + s];
        slot_of[tok * 2 + s] = pos;
    }
}

// xg[slot] = h2b[tok_idx[slot]]  (coalesced row copy, 2 slots per block)
__global__ __launch_bounds__(256) void gather_kernel(
    const short* __restrict__ h2b, const int* __restrict__ tok_idx,
    short* __restrict__ xg)
{
    int slot = blockIdx.x * 2 + (threadIdx.x >> 7);
    int c = (threadIdx.x & 127) * 8;
    int tok = tok_idx[slot];
    *(float4*)&xg[(size_t)slot * D + c] =
        *(const float4*)&h2b[(size_t)tok * D + c];
}

// out[tok] = x1[tok] + y[slot0] + y[slot1]
__global__ __launch_bounds__(256) void combine_kernel(
    const float* __restrict__ x1, const float* __restrict__ y,
    const int* __restrict__ slot_of, float* __restrict__ out)
{
    int tok = blockIdx.x, t = threadIdx.x;
    int s0 = slot_of[tok * 2], s1 = slot_of[tok * 2 + 1];
    float4 a = ((const float4*)(x1 + (size_t)tok * D))[t];
    float4 b = ((const float4*)(y + (size_t)s0 * D))[t];
    float4 c = ((const float4*)(y + (size_t)s1 * D))[t];
    float4 o;
    o.x = a.x + b.x + c.x; o.y = a.y + b.y + c.y;
    o.z = a.z + b.z + c.z; o.w = a.w + b.w + c.w;
    ((float4*)(out + (size_t)tok * D))[t] = o;
}

// ---------------------------------------------------------------------------
extern "C" void kernel_launch(void* const* d_in, const int* in_sizes, int n_in,
                              void* d_out, int out_size, void* d_ws, size_t ws_size,
                              hipStream_t stream)
{
    const float* x        = (const float*)d_in[0];
    const float* norm1_w  = (const float*)d_in[1];
    const float* wq       = (const float*)d_in[2];
    const float* bq       = (const float*)d_in[3];
    const float* wk       = (const float*)d_in[4];
    const float* bk       = (const float*)d_in[5];
    const float* wv       = (const float*)d_in[6];
    const float* bv       = (const float*)d_in[7];
    const float* wo       = (const float*)d_in[8];
    const float* bo       = (const float*)d_in[9];
    const float* sink     = (const float*)d_in[10];
    const float* norm2_w  = (const float*)d_in[11];
    const float* router_w = (const float*)d_in[12];
    const float* router_b = (const float*)d_in[13];
    const float* w1       = (const float*)d_in[14];
    const float* b1       = (const float*)d_in[15];
    const float* w2       = (const float*)d_in[16];
    const float* b2       = (const float*)d_in[17];
    float* out = (float*)d_out;

    // workspace layout
    char* w = (char*)d_ws;
    auto alloc = [&](size_t bytes) {
        char* p = w; w += (bytes + 255) & ~255ull; return p;
    };
    short* wqkvT = (short*)alloc((size_t)QKV_M * D * 2);
    short* woT   = (short*)alloc((size_t)D * D * 2);
    short* w1T   = (short*)alloc((size_t)E_ * HDIM * D * 2);
    short* w2T   = (short*)alloc((size_t)E_ * D * HDIM * 2);
    float* bqkv  = (float*)alloc(QKV_M * 4);
    float* rwT   = (float*)alloc((size_t)E_ * D * 4);          // 64 KB
    short* h_bf  = (short*)alloc((size_t)S * D * 2);
    float* qkv   = (float*)alloc((size_t)S * QKV_M * 4);
    float* x1    = (float*)alloc((size_t)S * D * 4);
    short* h2b   = (short*)alloc((size_t)S * D * 2);
    short* xg    = (short*)alloc((size_t)NSLOT * D * 2);
    float* yslot = (float*)alloc((size_t)NSLOT * D * 4);
    float* probs = (float*)alloc((size_t)NTOK * E_ * 4);       // 128 KB
    int*   offs     = (int*)alloc(17 * 4);
    int*   cursor   = (int*)alloc(16 * 4);
    int*   top_i    = (int*)alloc((size_t)NSLOT * 4);
    float* top_g    = (float*)alloc((size_t)NSLOT * 4);
    int*   tok_idx  = (int*)alloc((size_t)NSLOT * 4);
    float* tok_gate = (float*)alloc((size_t)NSLOT * 4);
    int*   slot_of  = (int*)alloc((size_t)NSLOT * 4);
    // aliases (lifetimes don't overlap):
    short* ao_bf = h_bf;          // h_bf dead after QKV GEMM
    short* hmid  = (short*)qkv;   // qkv dead after attention

    // 0) all weight prep in one launch (now includes rwT)
    tconv_all<<<18982, 256, 0, stream>>>(wq, wk, wv, wo, w1, w2, bq, bk, bv,
                                         router_w, wqkvT, woT, w1T, w2T,
                                         bqkv, rwT);

    // 1) h = rmsnorm(x) -> bf16
    rmsnorm_kernel<<<S, 256, 0, stream>>>(x, norm1_w, h_bf);

    // 2) fused QKV
    mgemm<0, 128><<<dim3(QKV_M / 64, S / 128), 256, 0, stream>>>(
        h_bf, wqkvT, bqkv, qkv, nullptr, nullptr, D, QKV_M, nullptr, nullptr);

    // 3) attention -> bf16 ao
    attn_kernel<<<dim3(S / QB, NKV), 256, 0, stream>>>(qkv, sink, ao_bf);

    // 4) x1 = x + ao@wo + bo
    mgemm<1, 128><<<dim3(D / 64, S / 128), 256, 0, stream>>>(
        ao_bf, woT, bo, x1, nullptr, x, D, D, nullptr, nullptr);

    // 5+6) fused rmsnorm2 + router (atomic-free)
    rms_router_kernel<<<NTOK, 256, 0, stream>>>(x1, norm2_w, h2b, rwT,
                                                router_b, probs, top_i, top_g);

    // 7) finalize: colsum/aux + histogram + offs/cursor
    finalize_kernel<<<1, 256, 0, stream>>>(probs, top_i, offs, cursor,
                                           out + (size_t)S * D);

    // 8) scatter token slots expert-contiguously (+ inverse slot map)
    scatter_kernel<<<(NTOK + 255) / 256, 256, 0, stream>>>(
        top_i, top_g, cursor, tok_idx, tok_gate, slot_of);

    // 8b) pre-gather activations into slot order
    gather_kernel<<<NSLOT / 2, 256, 0, stream>>>(h2b, tok_idx, xg);

    // 9) MoE GEMM1
    mgemm<2, 64><<<dim3(HDIM / 64, 32, E_), 256, 0, stream>>>(
        xg, w1T, b1, nullptr, hmid, nullptr, D, HDIM, offs, nullptr);

    // 10) MoE GEMM2
    mgemm<3, 64><<<dim3(D / 64, 32, E_), 256, 0, stream>>>(
        hmid, w2T, b2, yslot, nullptr, nullptr, HDIM, D, offs, tok_gate);

    // 11) out = x1 + yslot[slot0] + yslot[slot1]
    combine_kernel<<<NTOK, 256, 0, stream>>>(x1, yslot, slot_of, out);
}

// Round 9
// 297.296 us; speedup vs baseline: 2.9731x; 1.1094x over previous
//
#include <hip/hip_runtime.h>
#include <hip/hip_bf16.h>

// Problem constants
#define S     2048
#define D     1024
#define NH    8
#define NKV   2
#define HD    128
#define WS_   64
#define E_    16
#define HDIM  512
#define TOPK  2
#define NTOK  S
#define NSLOT (S*TOPK)         // 4096
#define QKV_M (D + 2*NKV*HD)   // 1536 fused q|k|v columns
#define KOFF  D                // 1024
#define VOFF  (D + NKV*HD)     // 1280
#define QB    8                // queries per attention block
#define WROWS (QB + WS_ - 1)   // 71 key rows per window
#define KPITCH 73              // KT key pitch (float4 units)
#define VPADF  132             // Vs row stride in floats

typedef __attribute__((ext_vector_type(8))) short bf16x8;
typedef __attribute__((ext_vector_type(4))) float floatx4;

__device__ inline short f2bf(float f) {
    __hip_bfloat16 b = __float2bfloat16(f);
    return *reinterpret_cast<short*>(&b);
}

// ---------------------------------------------------------------------------
// All weight prep in ONE launch: 6 transpose+convert regions + bias concat
// + fp32 router_w transpose (rwT[16][1024]).
// ---------------------------------------------------------------------------
__global__ __launch_bounds__(256) void tconv_all(
    const float* __restrict__ wq, const float* __restrict__ wk,
    const float* __restrict__ wv, const float* __restrict__ wo,
    const float* __restrict__ w1, const float* __restrict__ w2,
    const float* __restrict__ bq, const float* __restrict__ bk,
    const float* __restrict__ bv, const float* __restrict__ router_w,
    short* __restrict__ wqkvT, short* __restrict__ woT,
    short* __restrict__ w1T, short* __restrict__ w2T,
    float* __restrict__ bqkv, float* __restrict__ rwT)
{
    int id = blockIdx.x;
    if (id >= 18950) {                       // 32 router_w transpose blocks
        int ky = id - 18950;                 // 0..31
        int t = threadIdx.x;
        int r = t >> 4, c = t & 15;
        int k0 = ky * 32;
        rwT[c * D + k0 + r]      = router_w[(k0 + r) * E_ + c];
        rwT[c * D + k0 + r + 16] = router_w[(k0 + r + 16) * E_ + c];
        return;
    }
    if (id >= 18944) {                       // 6 bias-concat blocks
        int t = (id - 18944) * 256 + threadIdx.x;
        if (t < D) bqkv[t] = bq[t];
        else if (t < VOFF) bqkv[t] = bk[t - D];
        else bqkv[t] = bv[t - VOFF];
        return;
    }
    const float* in; short* outp; int K, M, mx, ky;
    if (id < 1024)      { in = wq; outp = wqkvT;                  K = D; M = D;   int l = id;        mx = l & 31; ky = l >> 5; }
    else if (id < 1280) { in = wk; outp = wqkvT + (size_t)KOFF*D; K = D; M = 256; int l = id - 1024; mx = l & 7;  ky = l >> 3; }
    else if (id < 1536) { in = wv; outp = wqkvT + (size_t)VOFF*D; K = D; M = 256; int l = id - 1280; mx = l & 7;  ky = l >> 3; }
    else if (id < 2560) { in = wo; outp = woT;                    K = D; M = D;   int l = id - 1536; mx = l & 31; ky = l >> 5; }
    else if (id < 10752){ int l = id - 2560;  int e = l >> 9; int r = l & 511;
                          in = w1 + (size_t)e * D * HDIM; outp = w1T + (size_t)e * D * HDIM;
                          K = D; M = HDIM; mx = r & 15; ky = r >> 4; }
    else                { int l = id - 10752; int e = l >> 9; int r = l & 511;
                          in = w2 + (size_t)e * D * HDIM; outp = w2T + (size_t)e * D * HDIM;
                          K = HDIM; M = D; mx = r & 31; ky = r >> 5; }
    __shared__ float tile[32][33];
    int t = threadIdx.x, r = t >> 3, c4 = (t & 7) * 4;
    int k0 = ky * 32, m0 = mx * 32;
    float4 v = *(const float4*)&in[(size_t)(k0 + r) * M + m0 + c4];
    tile[r][c4 + 0] = v.x; tile[r][c4 + 1] = v.y;
    tile[r][c4 + 2] = v.z; tile[r][c4 + 3] = v.w;
    __syncthreads();
    short4 o;
    o.x = f2bf(tile[c4 + 0][r]);
    o.y = f2bf(tile[c4 + 1][r]);
    o.z = f2bf(tile[c4 + 2][r]);
    o.w = f2bf(tile[c4 + 3][r]);
    *(short4*)&outp[(size_t)(m0 + r) * K + k0 + c4] = o;
}

// ---------------------------------------------------------------------------
// RMSNorm (attention pre-norm): fp32 in -> bf16 out
// ---------------------------------------------------------------------------
__global__ __launch_bounds__(256) void rmsnorm_kernel(
    const float* __restrict__ x, const float* __restrict__ w,
    short* __restrict__ outb)
{
    int row = blockIdx.x, t = threadIdx.x;
    float4 v = ((const float4*)(x + (size_t)row * D))[t];
    float ss = v.x*v.x + v.y*v.y + v.z*v.z + v.w*v.w;
    #pragma unroll
    for (int off = 32; off; off >>= 1) ss += __shfl_xor(ss, off, 64);
    __shared__ float red[4];
    if ((t & 63) == 0) red[t >> 6] = ss;
    __syncthreads();
    float total = red[0] + red[1] + red[2] + red[3];
    float scale = rsqrtf(total * (1.0f / (float)D) + 1e-6f);
    float4 wv = ((const float4*)w)[t];
    short4 ob;
    ob.x = f2bf(v.x * scale * wv.x); ob.y = f2bf(v.y * scale * wv.y);
    ob.z = f2bf(v.z * scale * wv.z); ob.w = f2bf(v.w * scale * wv.w);
    ((short4*)(outb + (size_t)row * D))[t] = ob;
}

// ---------------------------------------------------------------------------
// bf16 MFMA GEMM: C[N,M] = A[N,K](bf16) @ Bt[M,K]^T(bf16) + bias
// 64x64 tile, BK=64 (two stride-40 k-subtiles), LDS double-buffered:
// one barrier per iter; next-next tile's loads issued right after the
// buffer write (~1.5 iters of load latency hidden).
// STAGING (R8 bugfix): 4 threads/row, thread covers k-quarter (t&3)*16..+16
// via TWO float4 loads (+0,+8) -> every LDS short written.
// MFMA call order = R7-passing kernel (bitwise-identical numerics).
// V=0: C fp32 (QKV)  V=1: +bias+res (WO->x1)  V=2: MoE1 silu->bf16
// V=3: MoE2 gate-scaled store
// ---------------------------------------------------------------------------
template <int V>
__global__ __launch_bounds__(256) void mgemm(
    const short* __restrict__ A, const short* __restrict__ Bt,
    const float* __restrict__ bias, float* __restrict__ C,
    short* __restrict__ Cb, const float* __restrict__ res, int K, int M,
    const int* __restrict__ offs, const float* __restrict__ tok_gate)
{
    int e = (V >= 2) ? blockIdx.z : 0;
    const short* Bte = (V >= 2) ? Bt + (size_t)e * M * K : Bt;
    const float* be  = (V >= 2) ? bias + (size_t)e * M : bias;

    int row_lo, row_hi;
    if (V >= 2) {
        row_lo = offs[e] + blockIdx.y * 64;
        row_hi = offs[e + 1];
        if (row_lo >= row_hi) return;
    } else {
        row_lo = blockIdx.y * 64;
        row_hi = 1 << 30;
    }
    int col0 = blockIdx.x * 64;

    constexpr int SUB = 64 * 40;   // one 32-wide k-subtile of 64 rows (shorts)
    constexpr int BUF = 2 * SUB;   // one BK=64 buffer = 2 subtiles
    __shared__ short As[2 * BUF];  // 20.5 KB
    __shared__ short Bs[2 * BUF];  // 20.5 KB

    int t = threadIdx.x;
    int srow = t >> 2;             // 0..63
    int skq  = t & 3;              // k-quarter within BK=64
    int sgk  = skq * 16;           // global k offset (shorts)
    int ssub = skq >> 1;           // sub-tile index
    int soff = (skq & 1) * 16;     // offset within sub row (0 or 16)

    int  agrow = row_lo + srow;
    bool aval  = (V < 2) || (agrow < row_hi);
    int  asrc  = aval ? agrow : row_lo;
    const short* aptr = A   + (size_t)asrc * K + sgk;
    const short* bptr = Bte + (size_t)(col0 + srow) * K + sgk;
    short* as_w = &As[ssub * SUB + srow * 40 + soff];
    short* bs_w = &Bs[ssub * SUB + srow * 40 + soff];

    int lane = t & 63, wave = t >> 6;
    int wm = (wave & 1) * 32, wn = (wave >> 1) * 32;
    int rin = lane & 15, quad = lane >> 4;

    floatx4 acc[2][2];
    #pragma unroll
    for (int i = 0; i < 2; ++i)
        #pragma unroll
        for (int j = 0; j < 2; ++j)
            acc[i][j] = (floatx4){0.f, 0.f, 0.f, 0.f};

    // prologue: tile 0 -> buf0; prefetch tile 1 into VGPRs
    float4 va0 = *(const float4*)(aptr);
    float4 va1 = *(const float4*)(aptr + 8);
    float4 vb0 = *(const float4*)(bptr);
    float4 vb1 = *(const float4*)(bptr + 8);
    *(float4*)(as_w)     = va0;
    *(float4*)(as_w + 8) = va1;
    *(float4*)(bs_w)     = vb0;
    *(float4*)(bs_w + 8) = vb1;
    if (K > 64) {
        va0 = *(const float4*)(aptr + 64);
        va1 = *(const float4*)(aptr + 72);
        vb0 = *(const float4*)(bptr + 64);
        vb1 = *(const float4*)(bptr + 72);
    }
    __syncthreads();

    const int NIT = K >> 6;
    for (int it = 0; it < NIT; ++it) {
        int cur = it & 1, nxt = cur ^ 1;
        if (it + 1 < NIT) {
            *(float4*)(as_w + nxt * BUF)     = va0;  // waits vmcnt (tile it+1)
            *(float4*)(as_w + nxt * BUF + 8) = va1;
            *(float4*)(bs_w + nxt * BUF)     = vb0;
            *(float4*)(bs_w + nxt * BUF + 8) = vb1;
            if (it + 2 < NIT) {                      // issue it+2 immediately
                int k2 = (it + 2) << 6;
                va0 = *(const float4*)(aptr + k2);
                va1 = *(const float4*)(aptr + k2 + 8);
                vb0 = *(const float4*)(bptr + k2);
                vb1 = *(const float4*)(bptr + k2 + 8);
            }
        }
        #pragma unroll
        for (int s = 0; s < 2; ++s) {
            bf16x8 af[2], bfr[2];
            #pragma unroll
            for (int i = 0; i < 2; ++i)
                af[i] = *(const bf16x8*)&As[cur * BUF + s * SUB
                                            + (wm + i * 16 + rin) * 40 + quad * 8];
            #pragma unroll
            for (int j = 0; j < 2; ++j)
                bfr[j] = *(const bf16x8*)&Bs[cur * BUF + s * SUB
                                             + (wn + j * 16 + rin) * 40 + quad * 8];
            #pragma unroll
            for (int i = 0; i < 2; ++i)
                #pragma unroll
                for (int j = 0; j < 2; ++j)
                    acc[i][j] = __builtin_amdgcn_mfma_f32_16x16x32_bf16(
                        af[i], bfr[j], acc[i][j], 0, 0, 0);
        }
        __syncthreads();   // cur-reads done; nxt-writes visible next iter
    }

    // Epilogue. C/D layout: col = lane&15, row = quad*4 + reg  [m89-verified]
    #pragma unroll
    for (int i = 0; i < 2; ++i) {
        #pragma unroll
        for (int j = 0; j < 2; ++j) {
            int cg = col0 + wn + j * 16 + rin;
            #pragma unroll
            for (int rr = 0; rr < 4; ++rr) {
                int rg = row_lo + wm + i * 16 + quad * 4 + rr;
                float val = acc[i][j][rr];
                if (V == 0) {
                    C[(size_t)rg * M + cg] = val + be[cg];
                } else if (V == 1) {
                    C[(size_t)rg * M + cg] = val + be[cg] + res[(size_t)rg * M + cg];
                } else if (V == 2) {
                    if (rg < row_hi) {
                        float vb_ = val + be[cg];
                        Cb[(size_t)rg * M + cg] = f2bf(vb_ / (1.f + __expf(-vb_)));
                    }
                } else {
                    if (rg < row_hi)
                        C[(size_t)rg * M + cg] = tok_gate[rg] * (val + be[cg]);
                }
            }
        }
    }
}

// ---------------------------------------------------------------------------
// Sliding-window attention — fp32 math, conflict-free LDS (R5-proven)
// ---------------------------------------------------------------------------
__global__ __launch_bounds__(256) void attn_kernel(
    const float* __restrict__ qkv, const float* __restrict__ sink_ptr,
    short* __restrict__ ao)
{
    __shared__ __align__(16) float KT[32 * KPITCH * 4];
    __shared__ __align__(16) float Vs[WROWS * VPADF];
    __shared__ __align__(16) float Ps4[4][64][4];

    int qblk = blockIdx.x;
    int kvh  = blockIdx.y;
    int q0   = qblk * QB;
    int jbase = q0 - (WS_ - 1);

    int t = threadIdx.x;
    int c4 = (t & 31) * 4, c4g = t & 31;
    for (int r = t >> 5; r < WROWS; r += 8) {
        int j = jbase + r;
        float4 kv4 = make_float4(0.f, 0.f, 0.f, 0.f);
        float4 vv4 = make_float4(0.f, 0.f, 0.f, 0.f);
        if (j >= 0) {
            kv4 = *(const float4*)(qkv + (size_t)j * QKV_M + KOFF + kvh * HD + c4);
            vv4 = *(const float4*)(qkv + (size_t)j * QKV_M + VOFF + kvh * HD + c4);
        }
        *(float4*)&KT[(c4g * KPITCH + r) * 4] = kv4;
        *(float4*)&Vs[r * VPADF + c4] = vv4;
    }
    __syncthreads();

    int lane = t & 63, wv = t >> 6;
    float sink = sink_ptr[0];
    const float rscale = 0.08838834764831845f;

    #pragma unroll
    for (int g = 0; g < 2; ++g) {
        int qi = wv * 2 + g;
        int i  = q0 + qi;
        bool valid = (jbase + qi + lane) >= 0;

        float sc[4] = {0.f, 0.f, 0.f, 0.f};
        const float* qbase = qkv + (size_t)i * QKV_M + (kvh * 4) * HD;
        #pragma unroll
        for (int c = 0; c < 32; ++c) {
            float4 kx = *(const float4*)&KT[(c * KPITCH + qi + lane) * 4];
            #pragma unroll
            for (int hh = 0; hh < 4; ++hh) {
                float4 q4 = *(const float4*)(qbase + hh * HD + c * 4);
                sc[hh] += q4.x*kx.x + q4.y*kx.y + q4.z*kx.z + q4.w*kx.w;
            }
        }

        float pn[4];
        #pragma unroll
        for (int hh = 0; hh < 4; ++hh) {
            float s = valid ? sc[hh] * rscale : -1e30f;
            float m = s;
            #pragma unroll
            for (int off = 32; off; off >>= 1) m = fmaxf(m, __shfl_xor(m, off, 64));
            float mf = fmaxf(m, sink);
            float p  = __expf(s - mf);
            float ds = p;
            #pragma unroll
            for (int off = 32; off; off >>= 1) ds += __shfl_xor(ds, off, 64);
            pn[hh] = p / (ds + __expf(sink - mf));
        }
        *(float4*)&Ps4[wv][lane][0] = make_float4(pn[0], pn[1], pn[2], pn[3]);

        float o0=0,o1=0,o2=0,o3=0,o4=0,o5=0,o6=0,o7=0;
        const float* vp = &Vs[qi * VPADF + 2 * lane];
        #pragma unroll
        for (int jj = 0; jj < 64; ++jj) {
            float4 p4 = *(const float4*)&Ps4[wv][jj][0];
            float2 vv = *(const float2*)(vp + jj * VPADF);
            o0 += p4.x * vv.x; o1 += p4.x * vv.y;
            o2 += p4.y * vv.x; o3 += p4.y * vv.y;
            o4 += p4.z * vv.x; o5 += p4.z * vv.y;
            o6 += p4.w * vv.x; o7 += p4.w * vv.y;
        }
        short2 r0; r0.x = f2bf(o0); r0.y = f2bf(o1);
        short2 r1; r1.x = f2bf(o2); r1.y = f2bf(o3);
        short2 r2; r2.x = f2bf(o4); r2.y = f2bf(o5);
        short2 r3; r3.x = f2bf(o6); r3.y = f2bf(o7);
        ((short2*)(ao + (size_t)i * D + (kvh * 4 + 0) * HD))[lane] = r0;
        ((short2*)(ao + (size_t)i * D + (kvh * 4 + 1) * HD))[lane] = r1;
        ((short2*)(ao + (size_t)i * D + (kvh * 4 + 2) * HD))[lane] = r2;
        ((short2*)(ao + (size_t)i * D + (kvh * 4 + 3) * HD))[lane] = r3;
    }
}

// ---------------------------------------------------------------------------
// Fused RMSNorm2 + router (atomic-free; R7-proven)
// ---------------------------------------------------------------------------
__global__ __launch_bounds__(256) void rms_router_kernel(
    const float* __restrict__ x1, const float* __restrict__ w,
    short* __restrict__ h2b, const float* __restrict__ rwT,
    const float* __restrict__ rb, float* __restrict__ probs,
    int* __restrict__ top_i, float* __restrict__ top_g)
{
    int tok = blockIdx.x, t = threadIdx.x;
    __shared__ float hrow[D];
    float4 v = ((const float4*)(x1 + (size_t)tok * D))[t];
    float ss = v.x*v.x + v.y*v.y + v.z*v.z + v.w*v.w;
    #pragma unroll
    for (int off = 32; off; off >>= 1) ss += __shfl_xor(ss, off, 64);
    __shared__ float red[4];
    if ((t & 63) == 0) red[t >> 6] = ss;
    __syncthreads();
    float total = red[0] + red[1] + red[2] + red[3];
    float scale = rsqrtf(total * (1.0f / (float)D) + 1e-6f);
    float4 wv = ((const float4*)w)[t];
    float4 o;
    o.x = v.x * scale * wv.x; o.y = v.y * scale * wv.y;
    o.z = v.z * scale * wv.z; o.w = v.w * scale * wv.w;
    ((float4*)hrow)[t] = o;
    short4 ob;
    ob.x = f2bf(o.x); ob.y = f2bf(o.y); ob.z = f2bf(o.z); ob.w = f2bf(o.w);
    ((short4*)(h2b + (size_t)tok * D))[t] = ob;
    __syncthreads();

    int e = t & 15, seg = t >> 4;
    const float4* rwp = (const float4*)(rwT + (size_t)e * D + seg * 64);
    const float4* hp  = (const float4*)(hrow + seg * 64);
    float part = 0.f;
    #pragma unroll
    for (int i = 0; i < 16; ++i) {
        float4 a = hp[i];
        float4 b = rwp[i];
        part += a.x * b.x; part += a.y * b.y;
        part += a.z * b.z; part += a.w * b.w;
    }
    __shared__ float lpart[256];
    lpart[t] = part;
    __syncthreads();
    __shared__ float logits[E_];
    if (t < E_) {
        float sl = 0.f;
        for (int sg = 0; sg < 16; ++sg) sl += lpart[sg * 16 + t];
        logits[t] = (sl + rb[t]) * 10.0f;   // /0.1
    }
    __syncthreads();
    __shared__ float sm[2];
    if (t == 0) {
        float mx = logits[0];
        for (int x = 1; x < E_; ++x) mx = fmaxf(mx, logits[x]);
        float ps = 0.f;
        for (int x = 0; x < E_; ++x) ps += __expf(logits[x] - mx);
        sm[0] = mx; sm[1] = ps;
        int i0 = 0; float v0 = logits[0];
        for (int x = 1; x < E_; ++x) if (logits[x] > v0) { v0 = logits[x]; i0 = x; }
        int i1 = (i0 == 0) ? 1 : 0; float v1 = logits[i1];
        for (int x = 0; x < E_; ++x) {
            if (x == i0) continue;
            if (logits[x] > v1) { v1 = logits[x]; i1 = x; }
        }
        float e1 = __expf(v1 - v0);
        float g0 = 1.f / (1.f + e1);
        float g1 = e1 * g0;
        top_i[tok * 2 + 0] = i0; top_g[tok * 2 + 0] = g0;
        top_i[tok * 2 + 1] = i1; top_g[tok * 2 + 1] = g1;
    }
    __syncthreads();
    if (t < E_) probs[tok * E_ + t] = __expf(logits[t] - sm[0]) / sm[1];
}

// ---------------------------------------------------------------------------
// Finalize: colsum + aux from probs; expert histogram from top_i; offs/cursor.
// ---------------------------------------------------------------------------
__global__ __launch_bounds__(256) void finalize_kernel(
    const float* __restrict__ probs, const int* __restrict__ top_i,
    int* __restrict__ offs, int* __restrict__ cursor,
    float* __restrict__ aux_out)
{
    __shared__ float csum[E_];
    __shared__ int hist[E_];
    int t = threadIdx.x;
    if (t < E_) { csum[t] = 0.f; hist[t] = 0; }
    __syncthreads();

    int c = t & 15, g = t >> 4;
    float part = 0.f;
    for (int i = 0; i < NTOK / 16; ++i)
        part += probs[(size_t)(i * 16 + g) * E_ + c];
    atomicAdd(&csum[c], part);

    for (int i = 0; i < NSLOT / 256; ++i) {
        int eidx = top_i[i * 256 + t] & 15;   // mask: never index OOB
        atomicAdd(&hist[eidx], 1);
    }
    __syncthreads();

    if (t == 0) {
        int acc = 0;
        for (int e = 0; e < E_; ++e) { offs[e] = acc; cursor[e] = acc; acc += hist[e]; }
        offs[E_] = acc;
        float s = 0.f;
        for (int e = 0; e < E_; ++e) s += csum[e] * csum[e];
        *aux_out = s / (float)E_ * 1e-5f;
    }
}

__global__ __launch_bounds__(256) void scatter_kernel(
    const int* __restrict__ top_i, const float* __restrict__ top_g,
    int* __restrict__ cursor, int* __restrict__ tok_idx,
    float* __restrict__ tok_gate, int* __restrict__ slot_of)
{
    int tok = blockIdx.x * 256 + threadIdx.x;
    if (tok >= NTOK) return;
    for (int s = 0; s < TOPK; ++s) {
        int e = top_i[tok * 2 + s] & 15;      // mask: insurance vs NaN logits
        int pos = atomicAdd(&cursor[e], 1) & (NSLOT - 1);
        tok_idx[pos]  = tok;
        tok_gate[pos] = top_g[tok * 2 + s];
        slot_of[tok * 2 + s] = pos;
    }
}

// xg[slot] = h2b[tok_idx[slot]]  (coalesced row copy, 2 slots per block)
__global__ __launch_bounds__(256) void gather_kernel(
    const short* __restrict__ h2b, const int* __restrict__ tok_idx,
    short* __restrict__ xg)
{
    int slot = blockIdx.x * 2 + (threadIdx.x >> 7);
    int c = (threadIdx.x & 127) * 8;
    int tok = tok_idx[slot] & (NTOK - 1);
    *(float4*)&xg[(size_t)slot * D + c] =
        *(const float4*)&h2b[(size_t)tok * D + c];
}

// out[tok] = x1[tok] + y[slot0] + y[slot1]
__global__ __launch_bounds__(256) void combine_kernel(
    const float* __restrict__ x1, const float* __restrict__ y,
    const int* __restrict__ slot_of, float* __restrict__ out)
{
    int tok = blockIdx.x, t = threadIdx.x;
    int s0 = slot_of[tok * 2] & (NSLOT - 1), s1 = slot_of[tok * 2 + 1] & (NSLOT - 1);
    float4 a = ((const float4*)(x1 + (size_t)tok * D))[t];
    float4 b = ((const float4*)(y + (size_t)s0 * D))[t];
    float4 c = ((const float4*)(y + (size_t)s1 * D))[t];
    float4 o;
    o.x = a.x + b.x + c.x; o.y = a.y + b.y + c.y;
    o.z = a.z + b.z + c.z; o.w = a.w + b.w + c.w;
    ((float4*)(out + (size_t)tok * D))[t] = o;
}

// ---------------------------------------------------------------------------
extern "C" void kernel_launch(void* const* d_in, const int* in_sizes, int n_in,
                              void* d_out, int out_size, void* d_ws, size_t ws_size,
                              hipStream_t stream)
{
    const float* x        = (const float*)d_in[0];
    const float* norm1_w  = (const float*)d_in[1];
    const float* wq       = (const float*)d_in[2];
    const float* bq       = (const float*)d_in[3];
    const float* wk       = (const float*)d_in[4];
    const float* bk       = (const float*)d_in[5];
    const float* wv       = (const float*)d_in[6];
    const float* bv       = (const float*)d_in[7];
    const float* wo       = (const float*)d_in[8];
    const float* bo       = (const float*)d_in[9];
    const float* sink     = (const float*)d_in[10];
    const float* norm2_w  = (const float*)d_in[11];
    const float* router_w = (const float*)d_in[12];
    const float* router_b = (const float*)d_in[13];
    const float* w1       = (const float*)d_in[14];
    const float* b1       = (const float*)d_in[15];
    const float* w2       = (const float*)d_in[16];
    const float* b2       = (const float*)d_in[17];
    float* out = (float*)d_out;

    // workspace layout
    char* w = (char*)d_ws;
    auto alloc = [&](size_t bytes) {
        char* p = w; w += (bytes + 255) & ~255ull; return p;
    };
    short* wqkvT = (short*)alloc((size_t)QKV_M * D * 2);
    short* woT   = (short*)alloc((size_t)D * D * 2);
    short* w1T   = (short*)alloc((size_t)E_ * HDIM * D * 2);
    short* w2T   = (short*)alloc((size_t)E_ * D * HDIM * 2);
    float* bqkv  = (float*)alloc(QKV_M * 4);
    float* rwT   = (float*)alloc((size_t)E_ * D * 4);
    short* h_bf  = (short*)alloc((size_t)S * D * 2);
    float* qkv   = (float*)alloc((size_t)S * QKV_M * 4);
    float* x1    = (float*)alloc((size_t)S * D * 4);
    short* h2b   = (short*)alloc((size_t)S * D * 2);
    short* xg    = (short*)alloc((size_t)NSLOT * D * 2);
    float* yslot = (float*)alloc((size_t)NSLOT * D * 4);
    float* probs = (float*)alloc((size_t)NTOK * E_ * 4);
    int*   offs     = (int*)alloc(17 * 4);
    int*   cursor   = (int*)alloc(16 * 4);
    int*   top_i    = (int*)alloc((size_t)NSLOT * 4);
    float* top_g    = (float*)alloc((size_t)NSLOT * 4);
    int*   tok_idx  = (int*)alloc((size_t)NSLOT * 4);
    float* tok_gate = (float*)alloc((size_t)NSLOT * 4);
    int*   slot_of  = (int*)alloc((size_t)NSLOT * 4);
    // aliases (lifetimes don't overlap):
    short* ao_bf = h_bf;          // h_bf dead after QKV GEMM
    short* hmid  = (short*)qkv;   // qkv dead after attention

    // 0) all weight prep in one launch
    tconv_all<<<18982, 256, 0, stream>>>(wq, wk, wv, wo, w1, w2, bq, bk, bv,
                                         router_w, wqkvT, woT, w1T, w2T,
                                         bqkv, rwT);

    // 1) h = rmsnorm(x) -> bf16
    rmsnorm_kernel<<<S, 256, 0, stream>>>(x, norm1_w, h_bf);

    // 2) fused QKV   (768 blocks)
    mgemm<0><<<dim3(QKV_M / 64, S / 64), 256, 0, stream>>>(
        h_bf, wqkvT, bqkv, qkv, nullptr, nullptr, D, QKV_M, nullptr, nullptr);

    // 3) attention -> bf16 ao
    attn_kernel<<<dim3(S / QB, NKV), 256, 0, stream>>>(qkv, sink, ao_bf);

    // 4) x1 = x + ao@wo + bo   (512 blocks)
    mgemm<1><<<dim3(D / 64, S / 64), 256, 0, stream>>>(
        ao_bf, woT, bo, x1, nullptr, x, D, D, nullptr, nullptr);

    // 5+6) fused rmsnorm2 + router (atomic-free)
    rms_router_kernel<<<NTOK, 256, 0, stream>>>(x1, norm2_w, h2b, rwT,
                                                router_b, probs, top_i, top_g);

    // 7) finalize: colsum/aux + histogram + offs/cursor
    finalize_kernel<<<1, 256, 0, stream>>>(probs, top_i, offs, cursor,
                                           out + (size_t)S * D);

    // 8) scatter token slots expert-contiguously (+ inverse slot map)
    scatter_kernel<<<(NTOK + 255) / 256, 256, 0, stream>>>(
        top_i, top_g, cursor, tok_idx, tok_gate, slot_of);

    // 8b) pre-gather activations into slot order
    gather_kernel<<<NSLOT / 2, 256, 0, stream>>>(h2b, tok_idx, xg);

    // 9) MoE GEMM1  (y=64 tiles covers any expert skew up to NSLOT rows)
    mgemm<2><<<dim3(HDIM / 64, NSLOT / 64, E_), 256, 0, stream>>>(
        xg, w1T, b1, nullptr, hmid, nullptr, D, HDIM, offs, nullptr);

    // 10) MoE GEMM2
    mgemm<3><<<dim3(D / 64, NSLOT / 64, E_), 256, 0, stream>>>(
        hmid, w2T, b2, yslot, nullptr, nullptr, HDIM, D, offs, tok_gate);

    // 11) out = x1 + yslot[slot0] + yslot[slot1]
    combine_kernel<<<NTOK, 256, 0, stream>>>(x1, yslot, slot_of, out);
}